// Round 7
// baseline (728.959 us; speedup 1.0000x reference)
//
#include <hip/hip_runtime.h>
#include <hip/hip_fp16.h>

#define N_NODES 100000
#define IN_DIM 128
#define HID 64
#define NUM_GRAPHS 2048
#define CNE_MAX (1600000 + 3 * N_NODES)   // padded-to-4 CSR upper bound
#define BROWS 128                          // rows per bucket
#define NBUCK ((N_NODES + BROWS - 1) / BROWS)   // 782
#define NCHUNK 128                         // edge chunks (one block each)
#define TOTP (NBUCK * NCHUNK)              // 100096 partial counters
#define CAP 4096                           // LDS staging entries per bucket (mean ~2240)

// ---------------- build phase (NO per-edge global atomics anywhere) ----------------

// per-chunk bucket histogram in LDS -> partial[bucket][chunk] (bucket-major)
__global__ __launch_bounds__(256) void hist_partial(const int* __restrict__ dst,
                                                    int* __restrict__ partial,
                                                    int E, int chunk) {
    __shared__ int lh[NBUCK];
    int t = threadIdx.x, c = blockIdx.x;
    for (int b = t; b < NBUCK; b += 256) lh[b] = 0;
    __syncthreads();
    int lo = c * chunk, hi = min(lo + chunk, E);
    for (int i = lo + t; i < hi; i += 256) atomicAdd(&lh[dst[i] >> 7], 1);
    __syncthreads();
    for (int b = t; b < NBUCK; b += 256) partial[b * NCHUNK + c] = lh[b];
}

// generic hierarchical scan, phase 1: per-block (1024 elems) inclusive scan + block sums
__global__ void scan1(const int* __restrict__ counts, int* __restrict__ out1,
                      int* __restrict__ bsum, int n) {
    __shared__ int s[256];
    int t = threadIdx.x;
    int base = blockIdx.x * 1024 + t * 4;
    int v[4];
#pragma unroll
    for (int i = 0; i < 4; i++) v[i] = (base + i < n) ? counts[base + i] : 0;
    int tsum = v[0] + v[1] + v[2] + v[3];
    s[t] = tsum;
    __syncthreads();
    for (int off = 1; off < 256; off <<= 1) {
        int tv = (t >= off) ? s[t - off] : 0;
        __syncthreads();
        s[t] += tv;
        __syncthreads();
    }
    int excl = s[t] - tsum;
    if (t == 255) bsum[blockIdx.x] = s[255];
    int run = excl;
#pragma unroll
    for (int i = 0; i < 4; i++) {
        run += v[i];
        if (base + i < n) out1[base + i] = run;
    }
}

// phase 2: exclusive scan of block sums (nb <= 128)
__global__ void scan2(const int* __restrict__ bsum, int* __restrict__ boff, int nb) {
    __shared__ int s[128];
    int t = threadIdx.x;
    int v = (t < nb) ? bsum[t] : 0;
    s[t] = v;
    __syncthreads();
    for (int off = 1; off < 128; off <<= 1) {
        int tv = (t >= off) ? s[t - off] : 0;
        __syncthreads();
        s[t] += tv;
        __syncthreads();
    }
    if (t < nb) boff[t] = s[t] - v;
}

// phase 3 for row_ptr: add block offsets in place
__global__ void scan3(int* __restrict__ row_ptr, const int* __restrict__ boff, int n) {
    int i = blockIdx.x * blockDim.x + threadIdx.x;
    if (i == 0) row_ptr[0] = 0;
    if (i < n) row_ptr[i + 1] += boff[i >> 10];
}

// phase 3 for partial: exclusive = inclusive - self + block_off; emit part_off per bucket
__global__ void scan3p(const int* __restrict__ partial, const int* __restrict__ pincl,
                       const int* __restrict__ boff, int* __restrict__ base,
                       int* __restrict__ part_off, int E) {
    int i = blockIdx.x * blockDim.x + threadIdx.x;
    if (i < TOTP) {
        int v = pincl[i] + boff[i >> 10] - partial[i];
        base[i] = v;
        if ((i & (NCHUNK - 1)) == 0) part_off[i / NCHUNK] = v;
    }
    if (i == 0) part_off[NBUCK] = E;
}

// stable partition: each chunk re-reads its edges, takes positions from LDS cursors
__global__ __launch_bounds__(256) void partition_edges(const int* __restrict__ src,
                                                       const int* __restrict__ dst,
                                                       const int* __restrict__ base,
                                                       unsigned* __restrict__ part,
                                                       int E, int chunk) {
    __shared__ int cur[NBUCK];
    int t = threadIdx.x, c = blockIdx.x;
    for (int b = t; b < NBUCK; b += 256) cur[b] = base[b * NCHUNK + c];
    __syncthreads();
    int lo = c * chunk, hi = min(lo + chunk, E);
    for (int i = lo + t; i < hi; i += 256) {
        int s = src[i], d = dst[i];
        int pos = atomicAdd(&cur[d >> 7], 1);
        part[pos] = (unsigned)s | ((unsigned)(d & (BROWS - 1)) << 17);
    }
}

// per-bucket local-row counts from the strip -> padded degree + dis, coalesced writes
__global__ __launch_bounds__(256) void deg_dis(const unsigned* __restrict__ part,
                                               const int* __restrict__ part_off,
                                               int* __restrict__ pdeg,
                                               float* __restrict__ dis, int n) {
    __shared__ int cnt[BROWS];
    int t = threadIdx.x, b = blockIdx.x;
    int r0 = b * BROWS;
    if (t < BROWS) cnt[t] = 0;
    __syncthreads();
    for (int i = part_off[b] + t; i < part_off[b + 1]; i += 256)
        atomicAdd(&cnt[part[i] >> 17], 1);
    __syncthreads();
    int nrows = min(BROWS, n - r0);
    if (t < nrows) {
        int dg = cnt[t];
        pdeg[r0 + t] = (dg + 3) & ~3;               // pad row segment to multiple of 4
        dis[r0 + t] = rsqrtf((float)(dg + 1));      // +1 self-loop
    }
}

// per-bucket CSR build: LDS row cursors + LDS staging, coalesced writeout. Pads -> col N_NODES.
__global__ __launch_bounds__(256) void build_csr(const unsigned* __restrict__ part,
                                                 const int* __restrict__ part_off,
                                                 const int* __restrict__ row_ptr,
                                                 int* __restrict__ cne, int n) {
    __shared__ int fill[BROWS];
    __shared__ int stage[CAP];
    int b = blockIdx.x;
    int r0 = b * BROWS;
    int t = threadIdx.x;
    int nrows = min(BROWS, n - r0);
    int base = row_ptr[r0];
    int region = row_ptr[r0 + nrows] - base;
    for (int r = t; r < nrows; r += 256) fill[r] = row_ptr[r0 + r] - base;
    int i0 = part_off[b], i1 = part_off[b + 1];
    if (region <= CAP) {
        for (int i = t; i < region; i += 256) stage[i] = N_NODES;
        __syncthreads();
        for (int i = i0 + t; i < i1; i += 256) {
            unsigned pe = part[i];
            int pos = atomicAdd(&fill[pe >> 17], 1);
            stage[pos] = (int)(pe & 0x1FFFFu);
        }
        __syncthreads();
        for (int i = t; i < region; i += 256) cne[base + i] = stage[i];
    } else {  // fallback (statistically unreachable)
        for (int i = t; i < region; i += 256) cne[base + i] = N_NODES;
        __syncthreads();
        for (int i = i0 + t; i < i1; i += 256) {
            unsigned pe = part[i];
            int pos = atomicAdd(&fill[pe >> 17], 1);
            cne[base + pos] = (int)(pe & 0x1FFFFu);
        }
    }
}

// ---------------- per-layer compute ----------------

// lane = row, W broadcast via wave-uniform (SGPR) loads. Each wave-task: 64 rows x 32 cols.
// Per k: 32 v_fmac with SGPR W-operand -> 128 FLOP/instr (full VALU rate), no readlane.
template <int K>
__global__ __launch_bounds__(256) void gemm_rows(const float* __restrict__ X,
                                                 const float* __restrict__ W,
                                                 const float* __restrict__ dis,
                                                 __half* __restrict__ out, int n) {
    const int JT = 32;   // cols per wave-task
    int wave = threadIdx.x >> 6, lane = threadIdx.x & 63;
    int nslice = (n + 63) >> 6;
    int ntask = nslice * 2;               // 2 col-halves
    int wpb = blockDim.x >> 6;
    int tstride = gridDim.x * wpb;
    for (int task = blockIdx.x * wpb + wave; task < ntask; task += tstride) {
        int s = task >> 1;
        int jh = (task & 1) * JT;
        int row = (s << 6) + lane;
        bool valid = row < n;
        const float* xr = X + (size_t)(valid ? row : 0) * K;
        float acc[JT];
#pragma unroll
        for (int j = 0; j < JT; j++) acc[j] = 0.f;
        for (int kc = 0; kc < K; kc += 8) {
            float4 xa = *(const float4*)(xr + kc);
            float4 xb = *(const float4*)(xr + kc + 4);
            float xk[8] = {xa.x, xa.y, xa.z, xa.w, xb.x, xb.y, xb.z, xb.w};
#pragma unroll
            for (int kk = 0; kk < 8; kk++) {
                const float* wr = W + (kc + kk) * HID + jh;   // wave-uniform -> s_load
#pragma unroll
                for (int j = 0; j < JT; j++) acc[j] += xk[kk] * wr[j];
            }
        }
        if (valid) {
            float dr = dis[row];
            __half2* o = (__half2*)(out + (size_t)row * HID + jh);
#pragma unroll
            for (int j = 0; j < JT; j += 2)
                o[j >> 1] = __floats2half2_rn(dr * acc[j], dr * acc[j + 1]);
        }
    }
}

// out[row] = relu( dis[row] * (tmp2[row] + sum_cols tmp2[col]) + bias ); pads read zero row N.
// tmp2 is fp16: each row gather is 128 B (64 lanes x 2 B), halving L2-miss bytes.
__global__ __launch_bounds__(256) void aggregate(const __half* __restrict__ tmp,
                                                 const float* __restrict__ dis,
                                                 const int* __restrict__ row_ptr,
                                                 const int* __restrict__ cne,
                                                 const float* __restrict__ bias,
                                                 float* __restrict__ out, int n) {
    int wave = threadIdx.x >> 6, lane = threadIdx.x & 63;
    int wpb = blockDim.x >> 6;
    int stride = gridDim.x * wpb;
    float bl = bias[lane];
    for (int row = blockIdx.x * wpb + wave; row < n; row += stride) {
        float dr = dis[row];
        float acc0 = __half2float(tmp[row * HID + lane]);   // self-loop
        float acc1 = 0.f, acc2 = 0.f, acc3 = 0.f;
        int s = row_ptr[row], e = row_ptr[row + 1];
        if (s < e) {
            int4 c = *(const int4*)(cne + s);
            float v0 = __half2float(tmp[c.x * HID + lane]);
            float v1 = __half2float(tmp[c.y * HID + lane]);
            float v2 = __half2float(tmp[c.z * HID + lane]);
            float v3 = __half2float(tmp[c.w * HID + lane]);
            for (int t = s + 4; t < e; t += 4) {
                int4 d4 = *(const int4*)(cne + t);
                float u0 = __half2float(tmp[d4.x * HID + lane]);
                float u1 = __half2float(tmp[d4.y * HID + lane]);
                float u2 = __half2float(tmp[d4.z * HID + lane]);
                float u3 = __half2float(tmp[d4.w * HID + lane]);
                acc0 += v0; acc1 += v1; acc2 += v2; acc3 += v3;
                c = d4;
                v0 = u0; v1 = u1; v2 = u2; v3 = u3;
            }
            acc0 += v0; acc1 += v1; acc2 += v2; acc3 += v3;
        }
        float r = dr * ((acc0 + acc1) + (acc2 + acc3)) + bl;
        out[row * HID + lane] = fmaxf(r, 0.f);
    }
}

// one block (4 waves) per graph: mean+max pool, fused output dot
__global__ __launch_bounds__(256) void pool_kernel(const float* __restrict__ h,
                                                   const int* __restrict__ batch,
                                                   const float* __restrict__ Wout,
                                                   const float* __restrict__ bout,
                                                   float* __restrict__ d_out, int n) {
    __shared__ float ssum[4][64];
    __shared__ float smax[4][64];
    int g = blockIdx.x;
    int wave = threadIdx.x >> 6, j = threadIdx.x & 63;
    int lo = 0, hi = n;
    while (lo < hi) { int mid = (lo + hi) >> 1; if (batch[mid] < g) lo = mid + 1; else hi = mid; }
    int start = lo;
    hi = n;
    while (lo < hi) { int mid = (lo + hi) >> 1; if (batch[mid] < g + 1) lo = mid + 1; else hi = mid; }
    int end = lo;

    float sum = 0.f, mx = 0.f;   // h >= 0 post-relu; empty graph -> 0 per reference
    for (int i = start + wave; i < end; i += 4) {
        float v = h[(size_t)i * HID + j];
        sum += v;
        mx = fmaxf(mx, v);
    }
    ssum[wave][j] = sum;
    smax[wave][j] = mx;
    __syncthreads();
    if (wave == 0) {
        sum = (ssum[0][j] + ssum[1][j]) + (ssum[2][j] + ssum[3][j]);
        mx = fmaxf(fmaxf(smax[0][j], smax[1][j]), fmaxf(smax[2][j], smax[3][j]));
        float cnt = (float)(end - start);
        float mean = sum / fmaxf(cnt, 1.f);
        float* pooled = d_out + NUM_GRAPHS;
        pooled[(size_t)g * (2 * HID) + j] = mean;
        pooled[(size_t)g * (2 * HID) + HID + j] = mx;
        float c = mean * Wout[j] + mx * Wout[HID + j];
#pragma unroll
        for (int off = 32; off; off >>= 1) c += __shfl_down(c, off);
        if (j == 0) d_out[g] = c + bout[0];
    }
}

// ---------------- launch ----------------

extern "C" void kernel_launch(void* const* d_in, const int* in_sizes, int n_in,
                              void* d_out, int out_size, void* d_ws, size_t ws_size,
                              hipStream_t stream) {
    const float* x    = (const float*)d_in[0];
    const int*   edge = (const int*)d_in[1];
    const int*   batch= (const int*)d_in[2];
    const float* W1 = (const float*)d_in[3];  const float* b1 = (const float*)d_in[4];
    const float* W2 = (const float*)d_in[5];  const float* b2 = (const float*)d_in[6];
    const float* W3 = (const float*)d_in[7];  const float* b3 = (const float*)d_in[8];
    const float* W4 = (const float*)d_in[9];  const float* b4 = (const float*)d_in[10];
    const float* Wout = (const float*)d_in[11]; const float* bout = (const float*)d_in[12];
    float* out = (float*)d_out;

    const int N = N_NODES;
    const int E = in_sizes[1] / 2;
    const int* src = edge;
    const int* dst = edge + E;
    const int chunk = (E + NCHUNK - 1) / NCHUNK;

    char* p = (char*)d_ws;
    auto alloc = [&](size_t bytes) -> char* {
        char* r = p;
        p += (bytes + 255) & ~(size_t)255;
        return r;
    };
    int*      pdeg     = (int*)alloc((size_t)N * 4);
    int*      row_ptr  = (int*)alloc((size_t)(N + 1) * 4);
    int*      partial  = (int*)alloc((size_t)TOTP * 4);
    int*      pincl    = (int*)alloc((size_t)TOTP * 4);
    int*      pbase    = (int*)alloc((size_t)TOTP * 4);
    int*      part_off = (int*)alloc((size_t)(NBUCK + 1) * 4);
    unsigned* part     = (unsigned*)alloc((size_t)1600000 * 4);
    int*      cne      = (int*)alloc((size_t)CNE_MAX * 4);
    float*    dis      = (float*)alloc((size_t)N * 4);
    int*      bsum     = (int*)alloc(128 * 4);
    int*      boff     = (int*)alloc(128 * 4);
    __half*   tmp      = (__half*)alloc((size_t)(N + 1) * HID * 2);
    float*    hA       = (float*)alloc((size_t)N * HID * 4);

    hipMemsetAsync(tmp + (size_t)N * HID, 0, HID * 2, stream);   // zero row N (pad target)

    hist_partial<<<NCHUNK, 256, 0, stream>>>(dst, partial, E, chunk);
    // hierarchical exclusive scan of partial[TOTP]
    int nbp = (TOTP + 1023) / 1024;  // 98
    scan1<<<nbp, 256, 0, stream>>>(partial, pincl, bsum, TOTP);
    scan2<<<1, 128, 0, stream>>>(bsum, boff, nbp);
    scan3p<<<(TOTP + 255) / 256, 256, 0, stream>>>(partial, pincl, boff, pbase, part_off, E);
    partition_edges<<<NCHUNK, 256, 0, stream>>>(src, dst, pbase, part, E, chunk);
    deg_dis<<<NBUCK, 256, 0, stream>>>(part, part_off, pdeg, dis, N);

    int nb = (N + 1023) / 1024;  // 98
    scan1<<<nb, 256, 0, stream>>>(pdeg, row_ptr + 1, bsum, N);
    scan2<<<1, 128, 0, stream>>>(bsum, boff, nb);
    scan3<<<(N + 255) / 256, 256, 0, stream>>>(row_ptr, boff, N);
    build_csr<<<NBUCK, 256, 0, stream>>>(part, part_off, row_ptr, cne, N);

    const int AGG_BLOCKS = 2048;
    const int GEMM_BLOCKS = 782;   // 3128 wave-tasks ~= nslice*2 = 3126

    gemm_rows<IN_DIM><<<GEMM_BLOCKS, 256, 0, stream>>>(x, W1, dis, tmp, N);
    aggregate<<<AGG_BLOCKS, 256, 0, stream>>>(tmp, dis, row_ptr, cne, b1, hA, N);
    gemm_rows<HID><<<GEMM_BLOCKS, 256, 0, stream>>>(hA, W2, dis, tmp, N);
    aggregate<<<AGG_BLOCKS, 256, 0, stream>>>(tmp, dis, row_ptr, cne, b2, hA, N);
    gemm_rows<HID><<<GEMM_BLOCKS, 256, 0, stream>>>(hA, W3, dis, tmp, N);
    aggregate<<<AGG_BLOCKS, 256, 0, stream>>>(tmp, dis, row_ptr, cne, b3, hA, N);
    gemm_rows<HID><<<GEMM_BLOCKS, 256, 0, stream>>>(hA, W4, dis, tmp, N);
    aggregate<<<AGG_BLOCKS, 256, 0, stream>>>(tmp, dis, row_ptr, cne, b4, hA, N);

    pool_kernel<<<NUM_GRAPHS, 256, 0, stream>>>(hA, batch, Wout, bout, out, N);
}

// Round 8
// 561.706 us; speedup vs baseline: 1.2978x; 1.2978x over previous
//
#include <hip/hip_runtime.h>
#include <hip/hip_fp16.h>

#define N_NODES 100000
#define IN_DIM 128
#define HID 64
#define NUM_GRAPHS 2048
#define CNE_MAX (1600000 + 3 * N_NODES)   // padded-to-4 CSR upper bound
#define BROWS 128                          // rows per bucket
#define NBUCK ((N_NODES + BROWS - 1) / BROWS)   // 782
#define NCHUNK 128                         // edge chunks (one block each)
#define TOTP (NBUCK * NCHUNK)              // 100096 partial counters
#define CAP 4096                           // LDS staging entries per bucket (mean ~2240)

// ---------------- build phase (NO per-edge global atomics anywhere) ----------------

__global__ __launch_bounds__(256) void hist_partial(const int* __restrict__ dst,
                                                    int* __restrict__ partial,
                                                    int E, int chunk) {
    __shared__ int lh[NBUCK];
    int t = threadIdx.x, c = blockIdx.x;
    for (int b = t; b < NBUCK; b += 256) lh[b] = 0;
    __syncthreads();
    int lo = c * chunk, hi = min(lo + chunk, E);
    for (int i = lo + t; i < hi; i += 256) atomicAdd(&lh[dst[i] >> 7], 1);
    __syncthreads();
    for (int b = t; b < NBUCK; b += 256) partial[b * NCHUNK + c] = lh[b];
}

__global__ void scan1(const int* __restrict__ counts, int* __restrict__ out1,
                      int* __restrict__ bsum, int n) {
    __shared__ int s[256];
    int t = threadIdx.x;
    int base = blockIdx.x * 1024 + t * 4;
    int v[4];
#pragma unroll
    for (int i = 0; i < 4; i++) v[i] = (base + i < n) ? counts[base + i] : 0;
    int tsum = v[0] + v[1] + v[2] + v[3];
    s[t] = tsum;
    __syncthreads();
    for (int off = 1; off < 256; off <<= 1) {
        int tv = (t >= off) ? s[t - off] : 0;
        __syncthreads();
        s[t] += tv;
        __syncthreads();
    }
    int excl = s[t] - tsum;
    if (t == 255) bsum[blockIdx.x] = s[255];
    int run = excl;
#pragma unroll
    for (int i = 0; i < 4; i++) {
        run += v[i];
        if (base + i < n) out1[base + i] = run;
    }
}

__global__ void scan2(const int* __restrict__ bsum, int* __restrict__ boff, int nb) {
    __shared__ int s[128];
    int t = threadIdx.x;
    int v = (t < nb) ? bsum[t] : 0;
    s[t] = v;
    __syncthreads();
    for (int off = 1; off < 128; off <<= 1) {
        int tv = (t >= off) ? s[t - off] : 0;
        __syncthreads();
        s[t] += tv;
        __syncthreads();
    }
    if (t < nb) boff[t] = s[t] - v;
}

__global__ void scan3(int* __restrict__ row_ptr, const int* __restrict__ boff, int n) {
    int i = blockIdx.x * blockDim.x + threadIdx.x;
    if (i == 0) row_ptr[0] = 0;
    if (i < n) row_ptr[i + 1] += boff[i >> 10];
}

__global__ void scan3p(const int* __restrict__ partial, const int* __restrict__ pincl,
                       const int* __restrict__ boff, int* __restrict__ base,
                       int* __restrict__ part_off, int E) {
    int i = blockIdx.x * blockDim.x + threadIdx.x;
    if (i < TOTP) {
        int v = pincl[i] + boff[i >> 10] - partial[i];
        base[i] = v;
        if ((i & (NCHUNK - 1)) == 0) part_off[i / NCHUNK] = v;
    }
    if (i == 0) part_off[NBUCK] = E;
}

__global__ __launch_bounds__(256) void partition_edges(const int* __restrict__ src,
                                                       const int* __restrict__ dst,
                                                       const int* __restrict__ base,
                                                       unsigned* __restrict__ part,
                                                       int E, int chunk) {
    __shared__ int cur[NBUCK];
    int t = threadIdx.x, c = blockIdx.x;
    for (int b = t; b < NBUCK; b += 256) cur[b] = base[b * NCHUNK + c];
    __syncthreads();
    int lo = c * chunk, hi = min(lo + chunk, E);
    for (int i = lo + t; i < hi; i += 256) {
        int s = src[i], d = dst[i];
        int pos = atomicAdd(&cur[d >> 7], 1);
        part[pos] = (unsigned)s | ((unsigned)(d & (BROWS - 1)) << 17);
    }
}

__global__ __launch_bounds__(256) void deg_dis(const unsigned* __restrict__ part,
                                               const int* __restrict__ part_off,
                                               int* __restrict__ pdeg,
                                               float* __restrict__ dis, int n) {
    __shared__ int cnt[BROWS];
    int t = threadIdx.x, b = blockIdx.x;
    int r0 = b * BROWS;
    if (t < BROWS) cnt[t] = 0;
    __syncthreads();
    for (int i = part_off[b] + t; i < part_off[b + 1]; i += 256)
        atomicAdd(&cnt[part[i] >> 17], 1);
    __syncthreads();
    int nrows = min(BROWS, n - r0);
    if (t < nrows) {
        int dg = cnt[t];
        pdeg[r0 + t] = (dg + 3) & ~3;
        dis[r0 + t] = rsqrtf((float)(dg + 1));
    }
}

__global__ __launch_bounds__(256) void build_csr(const unsigned* __restrict__ part,
                                                 const int* __restrict__ part_off,
                                                 const int* __restrict__ row_ptr,
                                                 int* __restrict__ cne, int n) {
    __shared__ int fill[BROWS];
    __shared__ int stage[CAP];
    int b = blockIdx.x;
    int r0 = b * BROWS;
    int t = threadIdx.x;
    int nrows = min(BROWS, n - r0);
    int base = row_ptr[r0];
    int region = row_ptr[r0 + nrows] - base;
    for (int r = t; r < nrows; r += 256) fill[r] = row_ptr[r0 + r] - base;
    int i0 = part_off[b], i1 = part_off[b + 1];
    if (region <= CAP) {
        for (int i = t; i < region; i += 256) stage[i] = N_NODES;
        __syncthreads();
        for (int i = i0 + t; i < i1; i += 256) {
            unsigned pe = part[i];
            int pos = atomicAdd(&fill[pe >> 17], 1);
            stage[pos] = (int)(pe & 0x1FFFFu);
        }
        __syncthreads();
        for (int i = t; i < region; i += 256) cne[base + i] = stage[i];
    } else {
        for (int i = t; i < region; i += 256) cne[base + i] = N_NODES;
        __syncthreads();
        for (int i = i0 + t; i < i1; i += 256) {
            unsigned pe = part[i];
            int pos = atomicAdd(&fill[pe >> 17], 1);
            cne[base + pos] = (int)(pe & 0x1FFFFu);
        }
    }
}

// ---------------- per-layer compute ----------------

__device__ __forceinline__ float bcast(float v, int lane) {
    return __uint_as_float(__builtin_amdgcn_readlane(__float_as_uint(v), lane));
}

// R6-proven form: one wave per row, lane = col, W column held in per-lane registers.
template <int K>
__global__ __launch_bounds__(256) void gemm_rows(const float* __restrict__ X,
                                                 const float* __restrict__ W,
                                                 const float* __restrict__ dis,
                                                 __half* __restrict__ out, int n) {
    int wave = threadIdx.x >> 6, lane = threadIdx.x & 63;
    float w[K];
#pragma unroll
    for (int k = 0; k < K; k++) w[k] = W[k * HID + lane];
    int wpb = blockDim.x >> 6;
    int stride = gridDim.x * wpb;
    for (int row = blockIdx.x * wpb + wave; row < n; row += stride) {
        const float* xr = X + (size_t)row * K;
        float acc0 = 0.f, acc1 = 0.f;
        float xv0 = xr[lane];
        if constexpr (K == 128) {
            float xv1 = xr[lane + 64];
#pragma unroll
            for (int k = 0; k < 64; k += 2) {
                acc0 += bcast(xv0, k) * w[k];
                acc1 += bcast(xv0, k + 1) * w[k + 1];
            }
#pragma unroll
            for (int k = 0; k < 64; k += 2) {
                acc0 += bcast(xv1, k) * w[k + 64];
                acc1 += bcast(xv1, k + 1) * w[k + 65];
            }
        } else {
#pragma unroll
            for (int k = 0; k < 64; k += 2) {
                acc0 += bcast(xv0, k) * w[k];
                acc1 += bcast(xv0, k + 1) * w[k + 1];
            }
        }
        out[row * HID + lane] = __float2half(dis[row] * (acc0 + acc1));
    }
}

// FUSED: aggregate layer i  +  GEMM of layer i+1.
// h = relu(dis*(self + gather) + b); out2[row][lane] = (half) dis[row]*sum_k h_k*W2[k][lane].
// Gather waves stall on memory; matvec VALU work runs in that shadow on other waves.
__global__ __launch_bounds__(256) void agg_gemm(const __half* __restrict__ tmp,
                                                const float* __restrict__ dis,
                                                const int* __restrict__ row_ptr,
                                                const int* __restrict__ cne,
                                                const float* __restrict__ bias,
                                                const float* __restrict__ W2,
                                                __half* __restrict__ out2, int n) {
    int wave = threadIdx.x >> 6, lane = threadIdx.x & 63;
    float w[HID];
#pragma unroll
    for (int k = 0; k < HID; k++) w[k] = W2[k * HID + lane];
    int wpb = blockDim.x >> 6;
    int stride = gridDim.x * wpb;
    float bl = bias[lane];
    for (int row = blockIdx.x * wpb + wave; row < n; row += stride) {
        float dr = dis[row];
        float acc0 = __half2float(tmp[row * HID + lane]);   // self-loop
        float acc1 = 0.f, acc2 = 0.f, acc3 = 0.f;
        int s = row_ptr[row], e = row_ptr[row + 1];
        if (s < e) {
            int4 c = *(const int4*)(cne + s);
            float v0 = __half2float(tmp[c.x * HID + lane]);
            float v1 = __half2float(tmp[c.y * HID + lane]);
            float v2 = __half2float(tmp[c.z * HID + lane]);
            float v3 = __half2float(tmp[c.w * HID + lane]);
            for (int t = s + 4; t < e; t += 4) {
                int4 d4 = *(const int4*)(cne + t);
                float u0 = __half2float(tmp[d4.x * HID + lane]);
                float u1 = __half2float(tmp[d4.y * HID + lane]);
                float u2 = __half2float(tmp[d4.z * HID + lane]);
                float u3 = __half2float(tmp[d4.w * HID + lane]);
                acc0 += v0; acc1 += v1; acc2 += v2; acc3 += v3;
                c = d4;
                v0 = u0; v1 = u1; v2 = u2; v3 = u3;
            }
            acc0 += v0; acc1 += v1; acc2 += v2; acc3 += v3;
        }
        float h = fmaxf(dr * ((acc0 + acc1) + (acc2 + acc3)) + bl, 0.f);
        // matvec epilogue: h lives lane=col; readlane broadcasts h_k
        float a0 = 0.f, a1 = 0.f;
#pragma unroll
        for (int k = 0; k < 64; k += 2) {
            a0 += bcast(h, k) * w[k];
            a1 += bcast(h, k + 1) * w[k + 1];
        }
        out2[row * HID + lane] = __float2half(dr * (a0 + a1));
    }
}

// plain aggregate for the last layer (writes fp32 h for pooling)
__global__ __launch_bounds__(256) void aggregate(const __half* __restrict__ tmp,
                                                 const float* __restrict__ dis,
                                                 const int* __restrict__ row_ptr,
                                                 const int* __restrict__ cne,
                                                 const float* __restrict__ bias,
                                                 float* __restrict__ out, int n) {
    int wave = threadIdx.x >> 6, lane = threadIdx.x & 63;
    int wpb = blockDim.x >> 6;
    int stride = gridDim.x * wpb;
    float bl = bias[lane];
    for (int row = blockIdx.x * wpb + wave; row < n; row += stride) {
        float dr = dis[row];
        float acc0 = __half2float(tmp[row * HID + lane]);
        float acc1 = 0.f, acc2 = 0.f, acc3 = 0.f;
        int s = row_ptr[row], e = row_ptr[row + 1];
        if (s < e) {
            int4 c = *(const int4*)(cne + s);
            float v0 = __half2float(tmp[c.x * HID + lane]);
            float v1 = __half2float(tmp[c.y * HID + lane]);
            float v2 = __half2float(tmp[c.z * HID + lane]);
            float v3 = __half2float(tmp[c.w * HID + lane]);
            for (int t = s + 4; t < e; t += 4) {
                int4 d4 = *(const int4*)(cne + t);
                float u0 = __half2float(tmp[d4.x * HID + lane]);
                float u1 = __half2float(tmp[d4.y * HID + lane]);
                float u2 = __half2float(tmp[d4.z * HID + lane]);
                float u3 = __half2float(tmp[d4.w * HID + lane]);
                acc0 += v0; acc1 += v1; acc2 += v2; acc3 += v3;
                c = d4;
                v0 = u0; v1 = u1; v2 = u2; v3 = u3;
            }
            acc0 += v0; acc1 += v1; acc2 += v2; acc3 += v3;
        }
        float r = dr * ((acc0 + acc1) + (acc2 + acc3)) + bl;
        out[row * HID + lane] = fmaxf(r, 0.f);
    }
}

__global__ __launch_bounds__(256) void pool_kernel(const float* __restrict__ h,
                                                   const int* __restrict__ batch,
                                                   const float* __restrict__ Wout,
                                                   const float* __restrict__ bout,
                                                   float* __restrict__ d_out, int n) {
    __shared__ float ssum[4][64];
    __shared__ float smax[4][64];
    int g = blockIdx.x;
    int wave = threadIdx.x >> 6, j = threadIdx.x & 63;
    int lo = 0, hi = n;
    while (lo < hi) { int mid = (lo + hi) >> 1; if (batch[mid] < g) lo = mid + 1; else hi = mid; }
    int start = lo;
    hi = n;
    while (lo < hi) { int mid = (lo + hi) >> 1; if (batch[mid] < g + 1) lo = mid + 1; else hi = mid; }
    int end = lo;

    float sum = 0.f, mx = 0.f;
    for (int i = start + wave; i < end; i += 4) {
        float v = h[(size_t)i * HID + j];
        sum += v;
        mx = fmaxf(mx, v);
    }
    ssum[wave][j] = sum;
    smax[wave][j] = mx;
    __syncthreads();
    if (wave == 0) {
        sum = (ssum[0][j] + ssum[1][j]) + (ssum[2][j] + ssum[3][j]);
        mx = fmaxf(fmaxf(smax[0][j], smax[1][j]), fmaxf(smax[2][j], smax[3][j]));
        float cnt = (float)(end - start);
        float mean = sum / fmaxf(cnt, 1.f);
        float* pooled = d_out + NUM_GRAPHS;
        pooled[(size_t)g * (2 * HID) + j] = mean;
        pooled[(size_t)g * (2 * HID) + HID + j] = mx;
        float c = mean * Wout[j] + mx * Wout[HID + j];
#pragma unroll
        for (int off = 32; off; off >>= 1) c += __shfl_down(c, off);
        if (j == 0) d_out[g] = c + bout[0];
    }
}

// ---------------- launch ----------------

extern "C" void kernel_launch(void* const* d_in, const int* in_sizes, int n_in,
                              void* d_out, int out_size, void* d_ws, size_t ws_size,
                              hipStream_t stream) {
    const float* x    = (const float*)d_in[0];
    const int*   edge = (const int*)d_in[1];
    const int*   batch= (const int*)d_in[2];
    const float* W1 = (const float*)d_in[3];  const float* b1 = (const float*)d_in[4];
    const float* W2 = (const float*)d_in[5];  const float* b2 = (const float*)d_in[6];
    const float* W3 = (const float*)d_in[7];  const float* b3 = (const float*)d_in[8];
    const float* W4 = (const float*)d_in[9];  const float* b4 = (const float*)d_in[10];
    const float* Wout = (const float*)d_in[11]; const float* bout = (const float*)d_in[12];
    float* out = (float*)d_out;

    const int N = N_NODES;
    const int E = in_sizes[1] / 2;
    const int* src = edge;
    const int* dst = edge + E;
    const int chunk = (E + NCHUNK - 1) / NCHUNK;

    char* p = (char*)d_ws;
    auto alloc = [&](size_t bytes) -> char* {
        char* r = p;
        p += (bytes + 255) & ~(size_t)255;
        return r;
    };
    int*      pdeg     = (int*)alloc((size_t)N * 4);
    int*      row_ptr  = (int*)alloc((size_t)(N + 1) * 4);
    int*      partial  = (int*)alloc((size_t)TOTP * 4);
    int*      pincl    = (int*)alloc((size_t)TOTP * 4);
    int*      pbase    = (int*)alloc((size_t)TOTP * 4);
    int*      part_off = (int*)alloc((size_t)(NBUCK + 1) * 4);
    unsigned* part     = (unsigned*)alloc((size_t)1600000 * 4);
    int*      cne      = (int*)alloc((size_t)CNE_MAX * 4);
    float*    dis      = (float*)alloc((size_t)N * 4);
    int*      bsum     = (int*)alloc(128 * 4);
    int*      boff     = (int*)alloc(128 * 4);
    __half*   tmp      = (__half*)alloc((size_t)(N + 1) * HID * 2);
    __half*   tmp2     = (__half*)alloc((size_t)(N + 1) * HID * 2);
    float*    hA       = (float*)alloc((size_t)N * HID * 4);

    hipMemsetAsync(tmp + (size_t)N * HID, 0, HID * 2, stream);    // zero pad row N
    hipMemsetAsync(tmp2 + (size_t)N * HID, 0, HID * 2, stream);

    hist_partial<<<NCHUNK, 256, 0, stream>>>(dst, partial, E, chunk);
    int nbp = (TOTP + 1023) / 1024;
    scan1<<<nbp, 256, 0, stream>>>(partial, pincl, bsum, TOTP);
    scan2<<<1, 128, 0, stream>>>(bsum, boff, nbp);
    scan3p<<<(TOTP + 255) / 256, 256, 0, stream>>>(partial, pincl, boff, pbase, part_off, E);
    partition_edges<<<NCHUNK, 256, 0, stream>>>(src, dst, pbase, part, E, chunk);
    deg_dis<<<NBUCK, 256, 0, stream>>>(part, part_off, pdeg, dis, N);

    int nb = (N + 1023) / 1024;
    scan1<<<nb, 256, 0, stream>>>(pdeg, row_ptr + 1, bsum, N);
    scan2<<<1, 128, 0, stream>>>(bsum, boff, nb);
    scan3<<<(N + 255) / 256, 256, 0, stream>>>(row_ptr, boff, N);
    build_csr<<<NBUCK, 256, 0, stream>>>(part, part_off, row_ptr, cne, N);

    const int AGG_BLOCKS = 2048;

    gemm_rows<IN_DIM><<<1024, 256, 0, stream>>>(x, W1, dis, tmp, N);
    agg_gemm<<<AGG_BLOCKS, 256, 0, stream>>>(tmp, dis, row_ptr, cne, b1, W2, tmp2, N);
    agg_gemm<<<AGG_BLOCKS, 256, 0, stream>>>(tmp2, dis, row_ptr, cne, b2, W3, tmp, N);
    agg_gemm<<<AGG_BLOCKS, 256, 0, stream>>>(tmp, dis, row_ptr, cne, b3, W4, tmp2, N);
    aggregate<<<AGG_BLOCKS, 256, 0, stream>>>(tmp2, dis, row_ptr, cne, b4, hA, N);

    pool_kernel<<<NUM_GRAPHS, 256, 0, stream>>>(hA, batch, Wout, bout, out, N);
}

// Round 10
// 514.773 us; speedup vs baseline: 1.4161x; 1.0912x over previous
//
#include <hip/hip_runtime.h>
#include <hip/hip_fp16.h>

#define N_NODES 100000
#define IN_DIM 128
#define HID 64
#define NUM_GRAPHS 2048
#define CNE_MAX (1600000 + 3 * N_NODES)   // padded-to-4 CSR upper bound
#define BROWS 128                          // rows per bucket
#define NBUCK ((N_NODES + BROWS - 1) / BROWS)   // 782
#define NCHUNK 128                         // edge chunks (one block each)
#define TOTP (NBUCK * NCHUNK)              // 100096 partial counters
#define CAP 4096                           // LDS staging entries per bucket (mean ~2240)

// ---------------- build phase (NO per-edge global atomics anywhere) ----------------

__global__ __launch_bounds__(256) void hist_partial(const int* __restrict__ dst,
                                                    int* __restrict__ partial,
                                                    int E, int chunk) {
    __shared__ int lh[NBUCK];
    int t = threadIdx.x, c = blockIdx.x;
    for (int b = t; b < NBUCK; b += 256) lh[b] = 0;
    __syncthreads();
    int lo = c * chunk, hi = min(lo + chunk, E);
    for (int i = lo + t; i < hi; i += 256) atomicAdd(&lh[dst[i] >> 7], 1);
    __syncthreads();
    for (int b = t; b < NBUCK; b += 256) partial[b * NCHUNK + c] = lh[b];
}

__global__ void scan1(const int* __restrict__ counts, int* __restrict__ out1,
                      int* __restrict__ bsum, int n) {
    __shared__ int s[256];
    int t = threadIdx.x;
    int base = blockIdx.x * 1024 + t * 4;
    int v[4];
#pragma unroll
    for (int i = 0; i < 4; i++) v[i] = (base + i < n) ? counts[base + i] : 0;
    int tsum = v[0] + v[1] + v[2] + v[3];
    s[t] = tsum;
    __syncthreads();
    for (int off = 1; off < 256; off <<= 1) {
        int tv = (t >= off) ? s[t - off] : 0;
        __syncthreads();
        s[t] += tv;
        __syncthreads();
    }
    int excl = s[t] - tsum;
    if (t == 255) bsum[blockIdx.x] = s[255];
    int run = excl;
#pragma unroll
    for (int i = 0; i < 4; i++) {
        run += v[i];
        if (base + i < n) out1[base + i] = run;
    }
}

__global__ void scan2(const int* __restrict__ bsum, int* __restrict__ boff, int nb) {
    __shared__ int s[128];
    int t = threadIdx.x;
    int v = (t < nb) ? bsum[t] : 0;
    s[t] = v;
    __syncthreads();
    for (int off = 1; off < 128; off <<= 1) {
        int tv = (t >= off) ? s[t - off] : 0;
        __syncthreads();
        s[t] += tv;
        __syncthreads();
    }
    if (t < nb) boff[t] = s[t] - v;
}

__global__ void scan3(int* __restrict__ row_ptr, const int* __restrict__ boff, int n) {
    int i = blockIdx.x * blockDim.x + threadIdx.x;
    if (i == 0) row_ptr[0] = 0;
    if (i < n) row_ptr[i + 1] += boff[i >> 10];
}

__global__ void scan3p(const int* __restrict__ partial, const int* __restrict__ pincl,
                       const int* __restrict__ boff, int* __restrict__ base,
                       int* __restrict__ part_off, int E) {
    int i = blockIdx.x * blockDim.x + threadIdx.x;
    if (i < TOTP) {
        int v = pincl[i] + boff[i >> 10] - partial[i];
        base[i] = v;
        if ((i & (NCHUNK - 1)) == 0) part_off[i / NCHUNK] = v;
    }
    if (i == 0) part_off[NBUCK] = E;
}

__global__ __launch_bounds__(256) void partition_edges(const int* __restrict__ src,
                                                       const int* __restrict__ dst,
                                                       const int* __restrict__ base,
                                                       unsigned* __restrict__ part,
                                                       int E, int chunk) {
    __shared__ int cur[NBUCK];
    int t = threadIdx.x, c = blockIdx.x;
    for (int b = t; b < NBUCK; b += 256) cur[b] = base[b * NCHUNK + c];
    __syncthreads();
    int lo = c * chunk, hi = min(lo + chunk, E);
    for (int i = lo + t; i < hi; i += 256) {
        int s = src[i], d = dst[i];
        int pos = atomicAdd(&cur[d >> 7], 1);
        part[pos] = (unsigned)s | ((unsigned)(d & (BROWS - 1)) << 17);
    }
}

__global__ __launch_bounds__(256) void deg_dis(const unsigned* __restrict__ part,
                                               const int* __restrict__ part_off,
                                               int* __restrict__ pdeg,
                                               float* __restrict__ dis, int n) {
    __shared__ int cnt[BROWS];
    int t = threadIdx.x, b = blockIdx.x;
    int r0 = b * BROWS;
    if (t < BROWS) cnt[t] = 0;
    __syncthreads();
    for (int i = part_off[b] + t; i < part_off[b + 1]; i += 256)
        atomicAdd(&cnt[part[i] >> 17], 1);
    __syncthreads();
    int nrows = min(BROWS, n - r0);
    if (t < nrows) {
        int dg = cnt[t];
        pdeg[r0 + t] = (dg + 3) & ~3;
        dis[r0 + t] = rsqrtf((float)(dg + 1));
    }
}

__global__ __launch_bounds__(256) void build_csr(const unsigned* __restrict__ part,
                                                 const int* __restrict__ part_off,
                                                 const int* __restrict__ row_ptr,
                                                 int* __restrict__ cne, int n) {
    __shared__ int fill[BROWS];
    __shared__ int stage[CAP];
    int b = blockIdx.x;
    int r0 = b * BROWS;
    int t = threadIdx.x;
    int nrows = min(BROWS, n - r0);
    int base = row_ptr[r0];
    int region = row_ptr[r0 + nrows] - base;
    for (int r = t; r < nrows; r += 256) fill[r] = row_ptr[r0 + r] - base;
    int i0 = part_off[b], i1 = part_off[b + 1];
    if (region <= CAP) {
        for (int i = t; i < region; i += 256) stage[i] = N_NODES;
        __syncthreads();
        for (int i = i0 + t; i < i1; i += 256) {
            unsigned pe = part[i];
            int pos = atomicAdd(&fill[pe >> 17], 1);
            stage[pos] = (int)(pe & 0x1FFFFu);
        }
        __syncthreads();
        for (int i = t; i < region; i += 256) cne[base + i] = stage[i];
    } else {
        for (int i = t; i < region; i += 256) cne[base + i] = N_NODES;
        __syncthreads();
        for (int i = i0 + t; i < i1; i += 256) {
            unsigned pe = part[i];
            int pos = atomicAdd(&fill[pe >> 17], 1);
            cne[base + pos] = (int)(pe & 0x1FFFFu);
        }
    }
}

// ---------------- per-layer compute ----------------

__device__ __forceinline__ float bcast(float v, int lane) {
    return __uint_as_float(__builtin_amdgcn_readlane(__float_as_uint(v), lane));
}

// One wave per row, lane = col, W column in per-lane registers.
// R10: software-pipelined row loop (prefetch next row's x) + 4 independent
// (readlane, fmac) chains to cover the VALU->SGPR->VALU hazard.
template <int K>
__global__ __launch_bounds__(256) void gemm_rows(const float* __restrict__ X,
                                                 const float* __restrict__ W,
                                                 const float* __restrict__ dis,
                                                 __half* __restrict__ out, int n) {
    int wave = threadIdx.x >> 6, lane = threadIdx.x & 63;
    float w[K];
#pragma unroll
    for (int k = 0; k < K; k++) w[k] = W[k * HID + lane];
    int wpb = blockDim.x >> 6;
    int stride = gridDim.x * wpb;
    int row = blockIdx.x * wpb + wave;
    if (row >= n) return;
    float xv0 = X[(size_t)row * K + lane];
    float xv1 = 0.f;
    if constexpr (K == 128) xv1 = X[(size_t)row * K + lane + 64];
    while (true) {
        int nrow = row + stride;
        float nx0 = 0.f, nx1 = 0.f;
        if (nrow < n) {                       // prefetch next row before compute
            nx0 = X[(size_t)nrow * K + lane];
            if constexpr (K == 128) nx1 = X[(size_t)nrow * K + lane + 64];
        }
        float a0 = 0.f, a1 = 0.f, a2 = 0.f, a3 = 0.f;
#pragma unroll
        for (int k = 0; k < 64; k += 4) {
            a0 += bcast(xv0, k)     * w[k];
            a1 += bcast(xv0, k + 1) * w[k + 1];
            a2 += bcast(xv0, k + 2) * w[k + 2];
            a3 += bcast(xv0, k + 3) * w[k + 3];
        }
        if constexpr (K == 128) {
#pragma unroll
            for (int k = 0; k < 64; k += 4) {
                a0 += bcast(xv1, k)     * w[k + 64];
                a1 += bcast(xv1, k + 1) * w[k + 65];
                a2 += bcast(xv1, k + 2) * w[k + 66];
                a3 += bcast(xv1, k + 3) * w[k + 67];
            }
        }
        out[row * HID + lane] = __float2half(dis[row] * ((a0 + a1) + (a2 + a3)));
        row = nrow;
        if (row >= n) break;
        xv0 = nx0;
        xv1 = nx1;
    }
}

// out[row] = relu( dis[row] * (tmp2[row] + sum_cols tmp2[col]) + bias ); pads read zero row N.
__global__ __launch_bounds__(256) void aggregate(const __half* __restrict__ tmp,
                                                 const float* __restrict__ dis,
                                                 const int* __restrict__ row_ptr,
                                                 const int* __restrict__ cne,
                                                 const float* __restrict__ bias,
                                                 float* __restrict__ out, int n) {
    int wave = threadIdx.x >> 6, lane = threadIdx.x & 63;
    int wpb = blockDim.x >> 6;
    int stride = gridDim.x * wpb;
    float bl = bias[lane];
    for (int row = blockIdx.x * wpb + wave; row < n; row += stride) {
        float dr = dis[row];
        float acc0 = __half2float(tmp[row * HID + lane]);
        float acc1 = 0.f, acc2 = 0.f, acc3 = 0.f;
        int s = row_ptr[row], e = row_ptr[row + 1];
        if (s < e) {
            int4 c = *(const int4*)(cne + s);
            float v0 = __half2float(tmp[c.x * HID + lane]);
            float v1 = __half2float(tmp[c.y * HID + lane]);
            float v2 = __half2float(tmp[c.z * HID + lane]);
            float v3 = __half2float(tmp[c.w * HID + lane]);
            for (int t = s + 4; t < e; t += 4) {
                int4 d4 = *(const int4*)(cne + t);
                float u0 = __half2float(tmp[d4.x * HID + lane]);
                float u1 = __half2float(tmp[d4.y * HID + lane]);
                float u2 = __half2float(tmp[d4.z * HID + lane]);
                float u3 = __half2float(tmp[d4.w * HID + lane]);
                acc0 += v0; acc1 += v1; acc2 += v2; acc3 += v3;
                c = d4;
                v0 = u0; v1 = u1; v2 = u2; v3 = u3;
            }
            acc0 += v0; acc1 += v1; acc2 += v2; acc3 += v3;
        }
        float r = dr * ((acc0 + acc1) + (acc2 + acc3)) + bl;
        out[row * HID + lane] = fmaxf(r, 0.f);
    }
}

__global__ __launch_bounds__(256) void pool_kernel(const float* __restrict__ h,
                                                   const int* __restrict__ batch,
                                                   const float* __restrict__ Wout,
                                                   const float* __restrict__ bout,
                                                   float* __restrict__ d_out, int n) {
    __shared__ float ssum[4][64];
    __shared__ float smax[4][64];
    int g = blockIdx.x;
    int wave = threadIdx.x >> 6, j = threadIdx.x & 63;
    int lo = 0, hi = n;
    while (lo < hi) { int mid = (lo + hi) >> 1; if (batch[mid] < g) lo = mid + 1; else hi = mid; }
    int start = lo;
    hi = n;
    while (lo < hi) { int mid = (lo + hi) >> 1; if (batch[mid] < g + 1) lo = mid + 1; else hi = mid; }
    int end = lo;

    float sum = 0.f, mx = 0.f;
    for (int i = start + wave; i < end; i += 4) {
        float v = h[(size_t)i * HID + j];
        sum += v;
        mx = fmaxf(mx, v);
    }
    ssum[wave][j] = sum;
    smax[wave][j] = mx;
    __syncthreads();
    if (wave == 0) {
        sum = (ssum[0][j] + ssum[1][j]) + (ssum[2][j] + ssum[3][j]);
        mx = fmaxf(fmaxf(smax[0][j], smax[1][j]), fmaxf(smax[2][j], smax[3][j]));
        float cnt = (float)(end - start);
        float mean = sum / fmaxf(cnt, 1.f);
        float* pooled = d_out + NUM_GRAPHS;
        pooled[(size_t)g * (2 * HID) + j] = mean;
        pooled[(size_t)g * (2 * HID) + HID + j] = mx;
        float c = mean * Wout[j] + mx * Wout[HID + j];
#pragma unroll
        for (int off = 32; off; off >>= 1) c += __shfl_down(c, off);
        if (j == 0) d_out[g] = c + bout[0];
    }
}

// ---------------- launch ----------------

extern "C" void kernel_launch(void* const* d_in, const int* in_sizes, int n_in,
                              void* d_out, int out_size, void* d_ws, size_t ws_size,
                              hipStream_t stream) {
    const float* x    = (const float*)d_in[0];
    const int*   edge = (const int*)d_in[1];
    const int*   batch= (const int*)d_in[2];
    const float* W1 = (const float*)d_in[3];  const float* b1 = (const float*)d_in[4];
    const float* W2 = (const float*)d_in[5];  const float* b2 = (const float*)d_in[6];
    const float* W3 = (const float*)d_in[7];  const float* b3 = (const float*)d_in[8];
    const float* W4 = (const float*)d_in[9];  const float* b4 = (const float*)d_in[10];
    const float* Wout = (const float*)d_in[11]; const float* bout = (const float*)d_in[12];
    float* out = (float*)d_out;

    const int N = N_NODES;
    const int E = in_sizes[1] / 2;
    const int* src = edge;
    const int* dst = edge + E;
    const int chunk = (E + NCHUNK - 1) / NCHUNK;

    char* p = (char*)d_ws;
    auto alloc = [&](size_t bytes) -> char* {
        char* r = p;
        p += (bytes + 255) & ~(size_t)255;
        return r;
    };
    int*      pdeg     = (int*)alloc((size_t)N * 4);
    int*      row_ptr  = (int*)alloc((size_t)(N + 1) * 4);
    int*      partial  = (int*)alloc((size_t)TOTP * 4);
    int*      pincl    = (int*)alloc((size_t)TOTP * 4);
    int*      pbase    = (int*)alloc((size_t)TOTP * 4);
    int*      part_off = (int*)alloc((size_t)(NBUCK + 1) * 4);
    unsigned* part     = (unsigned*)alloc((size_t)1600000 * 4);
    int*      cne      = (int*)alloc((size_t)CNE_MAX * 4);
    float*    dis      = (float*)alloc((size_t)N * 4);
    int*      bsum     = (int*)alloc(128 * 4);
    int*      boff     = (int*)alloc(128 * 4);
    __half*   tmp      = (__half*)alloc((size_t)(N + 1) * HID * 2);
    float*    hA       = (float*)alloc((size_t)N * HID * 4);

    hipMemsetAsync(tmp + (size_t)N * HID, 0, HID * 2, stream);   // zero pad row N

    hist_partial<<<NCHUNK, 256, 0, stream>>>(dst, partial, E, chunk);
    int nbp = (TOTP + 1023) / 1024;
    scan1<<<nbp, 256, 0, stream>>>(partial, pincl, bsum, TOTP);
    scan2<<<1, 128, 0, stream>>>(bsum, boff, nbp);
    scan3p<<<(TOTP + 255) / 256, 256, 0, stream>>>(partial, pincl, boff, pbase, part_off, E);
    partition_edges<<<NCHUNK, 256, 0, stream>>>(src, dst, pbase, part, E, chunk);
    deg_dis<<<NBUCK, 256, 0, stream>>>(part, part_off, pdeg, dis, N);

    int nb = (N + 1023) / 1024;
    scan1<<<nb, 256, 0, stream>>>(pdeg, row_ptr + 1, bsum, N);
    scan2<<<1, 128, 0, stream>>>(bsum, boff, nb);
    scan3<<<(N + 255) / 256, 256, 0, stream>>>(row_ptr, boff, N);
    build_csr<<<NBUCK, 256, 0, stream>>>(part, part_off, row_ptr, cne, N);

    const int AGG_BLOCKS = 2048;

    gemm_rows<IN_DIM><<<1024, 256, 0, stream>>>(x, W1, dis, tmp, N);
    aggregate<<<AGG_BLOCKS, 256, 0, stream>>>(tmp, dis, row_ptr, cne, b1, hA, N);
    gemm_rows<HID><<<2048, 256, 0, stream>>>(hA, W2, dis, tmp, N);
    aggregate<<<AGG_BLOCKS, 256, 0, stream>>>(tmp, dis, row_ptr, cne, b2, hA, N);
    gemm_rows<HID><<<2048, 256, 0, stream>>>(hA, W3, dis, tmp, N);
    aggregate<<<AGG_BLOCKS, 256, 0, stream>>>(tmp, dis, row_ptr, cne, b3, hA, N);
    gemm_rows<HID><<<2048, 256, 0, stream>>>(hA, W4, dis, tmp, N);
    aggregate<<<AGG_BLOCKS, 256, 0, stream>>>(tmp, dis, row_ptr, cne, b4, hA, N);

    pool_kernel<<<NUM_GRAPHS, 256, 0, stream>>>(hA, batch, Wout, bout, out, N);
}

// Round 11
// 433.761 us; speedup vs baseline: 1.6806x; 1.1868x over previous
//
#include <hip/hip_runtime.h>
#include <hip/hip_fp16.h>

#define N_NODES 100000
#define IN_DIM 128
#define HID 64
#define NUM_GRAPHS 2048
#define CNE_MAX (1600000 + 3 * N_NODES)   // padded-to-4 CSR upper bound
#define BROWS 128                          // rows per bucket
#define NBUCK ((N_NODES + BROWS - 1) / BROWS)   // 782
#define NCHUNK 128                         // edge chunks (one block each)
#define TOTP (NBUCK * NCHUNK)              // 100096 partial counters
#define CAP 4096                           // LDS staging entries per bucket (mean ~2240)

typedef _Float16 h8 __attribute__((ext_vector_type(8)));
typedef float f4 __attribute__((ext_vector_type(4)));

// ---------------- build phase (NO per-edge global atomics anywhere) ----------------

__global__ __launch_bounds__(256) void hist_partial(const int* __restrict__ dst,
                                                    int* __restrict__ partial,
                                                    int E, int chunk) {
    __shared__ int lh[NBUCK];
    int t = threadIdx.x, c = blockIdx.x;
    for (int b = t; b < NBUCK; b += 256) lh[b] = 0;
    __syncthreads();
    int lo = c * chunk, hi = min(lo + chunk, E);
    for (int i = lo + t; i < hi; i += 256) atomicAdd(&lh[dst[i] >> 7], 1);
    __syncthreads();
    for (int b = t; b < NBUCK; b += 256) partial[b * NCHUNK + c] = lh[b];
}

__global__ void scan1(const int* __restrict__ counts, int* __restrict__ out1,
                      int* __restrict__ bsum, int n) {
    __shared__ int s[256];
    int t = threadIdx.x;
    int base = blockIdx.x * 1024 + t * 4;
    int v[4];
#pragma unroll
    for (int i = 0; i < 4; i++) v[i] = (base + i < n) ? counts[base + i] : 0;
    int tsum = v[0] + v[1] + v[2] + v[3];
    s[t] = tsum;
    __syncthreads();
    for (int off = 1; off < 256; off <<= 1) {
        int tv = (t >= off) ? s[t - off] : 0;
        __syncthreads();
        s[t] += tv;
        __syncthreads();
    }
    int excl = s[t] - tsum;
    if (t == 255) bsum[blockIdx.x] = s[255];
    int run = excl;
#pragma unroll
    for (int i = 0; i < 4; i++) {
        run += v[i];
        if (base + i < n) out1[base + i] = run;
    }
}

__global__ void scan2(const int* __restrict__ bsum, int* __restrict__ boff, int nb) {
    __shared__ int s[128];
    int t = threadIdx.x;
    int v = (t < nb) ? bsum[t] : 0;
    s[t] = v;
    __syncthreads();
    for (int off = 1; off < 128; off <<= 1) {
        int tv = (t >= off) ? s[t - off] : 0;
        __syncthreads();
        s[t] += tv;
        __syncthreads();
    }
    if (t < nb) boff[t] = s[t] - v;
}

__global__ void scan3(int* __restrict__ row_ptr, const int* __restrict__ boff, int n) {
    int i = blockIdx.x * blockDim.x + threadIdx.x;
    if (i == 0) row_ptr[0] = 0;
    if (i < n) row_ptr[i + 1] += boff[i >> 10];
}

__global__ void scan3p(const int* __restrict__ partial, const int* __restrict__ pincl,
                       const int* __restrict__ boff, int* __restrict__ base,
                       int* __restrict__ part_off, int E) {
    int i = blockIdx.x * blockDim.x + threadIdx.x;
    if (i < TOTP) {
        int v = pincl[i] + boff[i >> 10] - partial[i];
        base[i] = v;
        if ((i & (NCHUNK - 1)) == 0) part_off[i / NCHUNK] = v;
    }
    if (i == 0) part_off[NBUCK] = E;
}

__global__ __launch_bounds__(256) void partition_edges(const int* __restrict__ src,
                                                       const int* __restrict__ dst,
                                                       const int* __restrict__ base,
                                                       unsigned* __restrict__ part,
                                                       int E, int chunk) {
    __shared__ int cur[NBUCK];
    int t = threadIdx.x, c = blockIdx.x;
    for (int b = t; b < NBUCK; b += 256) cur[b] = base[b * NCHUNK + c];
    __syncthreads();
    int lo = c * chunk, hi = min(lo + chunk, E);
    for (int i = lo + t; i < hi; i += 256) {
        int s = src[i], d = dst[i];
        int pos = atomicAdd(&cur[d >> 7], 1);
        part[pos] = (unsigned)s | ((unsigned)(d & (BROWS - 1)) << 17);
    }
}

__global__ __launch_bounds__(256) void deg_dis(const unsigned* __restrict__ part,
                                               const int* __restrict__ part_off,
                                               int* __restrict__ pdeg,
                                               float* __restrict__ dis, int n) {
    __shared__ int cnt[BROWS];
    int t = threadIdx.x, b = blockIdx.x;
    int r0 = b * BROWS;
    if (t < BROWS) cnt[t] = 0;
    __syncthreads();
    for (int i = part_off[b] + t; i < part_off[b + 1]; i += 256)
        atomicAdd(&cnt[part[i] >> 17], 1);
    __syncthreads();
    int nrows = min(BROWS, n - r0);
    if (t < nrows) {
        int dg = cnt[t];
        pdeg[r0 + t] = (dg + 3) & ~3;
        dis[r0 + t] = rsqrtf((float)(dg + 1));
    }
}

__global__ __launch_bounds__(256) void build_csr(const unsigned* __restrict__ part,
                                                 const int* __restrict__ part_off,
                                                 const int* __restrict__ row_ptr,
                                                 int* __restrict__ cne, int n) {
    __shared__ int fill[BROWS];
    __shared__ int stage[CAP];
    int b = blockIdx.x;
    int r0 = b * BROWS;
    int t = threadIdx.x;
    int nrows = min(BROWS, n - r0);
    int base = row_ptr[r0];
    int region = row_ptr[r0 + nrows] - base;
    for (int r = t; r < nrows; r += 256) fill[r] = row_ptr[r0 + r] - base;
    int i0 = part_off[b], i1 = part_off[b + 1];
    if (region <= CAP) {
        for (int i = t; i < region; i += 256) stage[i] = N_NODES;
        __syncthreads();
        for (int i = i0 + t; i < i1; i += 256) {
            unsigned pe = part[i];
            int pos = atomicAdd(&fill[pe >> 17], 1);
            stage[pos] = (int)(pe & 0x1FFFFu);
        }
        __syncthreads();
        for (int i = t; i < region; i += 256) cne[base + i] = stage[i];
    } else {
        for (int i = t; i < region; i += 256) cne[base + i] = N_NODES;
        __syncthreads();
        for (int i = i0 + t; i < i1; i += 256) {
            unsigned pe = part[i];
            int pos = atomicAdd(&fill[pe >> 17], 1);
            cne[base + pos] = (int)(pe & 0x1FFFFu);
        }
    }
}

// ---------------- per-layer compute ----------------

// MFMA GEMM: out[row][col] = (half) dis[row] * sum_k X[row][k] * W[k][col]
// One wave per 16-row tile (N % 16 == 0). A: fp32->fp16 in-register.
// B-fragments built in-register from fp32 W (no transposed copy, no extra ws).
// Layouts (verified R9 first-call + guide m89/m91): A[m=lane&15][k=quad*8+j];
// B[k=quad*8+j][n=lane&15]; C/D col=lane&15, row=quad*4+reg.
template <int K>
__global__ __launch_bounds__(256) void gemm_mfma(const float* __restrict__ X,
                                                 const float* __restrict__ W,
                                                 const float* __restrict__ dis,
                                                 __half* __restrict__ out, int n) {
    const int KS = K / 32;
    int wave = threadIdx.x >> 6, lane = threadIdx.x & 63;
    int quad = lane >> 4, l16 = lane & 15;
    h8 b[4][KS];
#pragma unroll
    for (int ct = 0; ct < 4; ct++)
#pragma unroll
        for (int ks = 0; ks < KS; ks++)
#pragma unroll
            for (int j = 0; j < 8; j++)
                b[ct][ks][j] = (_Float16)W[(ks * 32 + quad * 8 + j) * HID + ct * 16 + l16];
    int ntile = n >> 4;
    int wpb = blockDim.x >> 6;
    int stride = gridDim.x * wpb;
    for (int rt = blockIdx.x * wpb + wave; rt < ntile; rt += stride) {
        int row0 = rt << 4;
        const float* xr = X + (size_t)(row0 + l16) * K + quad * 8;
        f4 acc[4];
#pragma unroll
        for (int ct = 0; ct < 4; ct++) acc[ct] = (f4)(0.f);
#pragma unroll
        for (int ks = 0; ks < KS; ks++) {
            float4 xa = *(const float4*)(xr + ks * 32);
            float4 xb = *(const float4*)(xr + ks * 32 + 4);
            h8 a;
            a[0] = (_Float16)xa.x; a[1] = (_Float16)xa.y;
            a[2] = (_Float16)xa.z; a[3] = (_Float16)xa.w;
            a[4] = (_Float16)xb.x; a[5] = (_Float16)xb.y;
            a[6] = (_Float16)xb.z; a[7] = (_Float16)xb.w;
#pragma unroll
            for (int ct = 0; ct < 4; ct++)
                acc[ct] = __builtin_amdgcn_mfma_f32_16x16x32_f16(a, b[ct][ks], acc[ct], 0, 0, 0);
        }
        int r0 = row0 + quad * 4;
        float4 dv = *(const float4*)(dis + r0);
        float dd[4] = {dv.x, dv.y, dv.z, dv.w};
#pragma unroll
        for (int reg = 0; reg < 4; reg++) {
            __half* orow = out + (size_t)(r0 + reg) * HID + l16;
            orow[0]  = __float2half(dd[reg] * acc[0][reg]);
            orow[16] = __float2half(dd[reg] * acc[1][reg]);
            orow[32] = __float2half(dd[reg] * acc[2][reg]);
            orow[48] = __float2half(dd[reg] * acc[3][reg]);
        }
    }
}

// out[row] = relu( dis[row] * (tmp2[row] + sum_cols tmp2[col]) + bias ); pads read zero row N.
__global__ __launch_bounds__(256) void aggregate(const __half* __restrict__ tmp,
                                                 const float* __restrict__ dis,
                                                 const int* __restrict__ row_ptr,
                                                 const int* __restrict__ cne,
                                                 const float* __restrict__ bias,
                                                 float* __restrict__ out, int n) {
    int wave = threadIdx.x >> 6, lane = threadIdx.x & 63;
    int wpb = blockDim.x >> 6;
    int stride = gridDim.x * wpb;
    float bl = bias[lane];
    for (int row = blockIdx.x * wpb + wave; row < n; row += stride) {
        float dr = dis[row];
        float acc0 = __half2float(tmp[row * HID + lane]);
        float acc1 = 0.f, acc2 = 0.f, acc3 = 0.f;
        int s = row_ptr[row], e = row_ptr[row + 1];
        if (s < e) {
            int4 c = *(const int4*)(cne + s);
            float v0 = __half2float(tmp[c.x * HID + lane]);
            float v1 = __half2float(tmp[c.y * HID + lane]);
            float v2 = __half2float(tmp[c.z * HID + lane]);
            float v3 = __half2float(tmp[c.w * HID + lane]);
            for (int t = s + 4; t < e; t += 4) {
                int4 d4 = *(const int4*)(cne + t);
                float u0 = __half2float(tmp[d4.x * HID + lane]);
                float u1 = __half2float(tmp[d4.y * HID + lane]);
                float u2 = __half2float(tmp[d4.z * HID + lane]);
                float u3 = __half2float(tmp[d4.w * HID + lane]);
                acc0 += v0; acc1 += v1; acc2 += v2; acc3 += v3;
                c = d4;
                v0 = u0; v1 = u1; v2 = u2; v3 = u3;
            }
            acc0 += v0; acc1 += v1; acc2 += v2; acc3 += v3;
        }
        float r = dr * ((acc0 + acc1) + (acc2 + acc3)) + bl;
        out[row * HID + lane] = fmaxf(r, 0.f);
    }
}

__global__ __launch_bounds__(256) void pool_kernel(const float* __restrict__ h,
                                                   const int* __restrict__ batch,
                                                   const float* __restrict__ Wout,
                                                   const float* __restrict__ bout,
                                                   float* __restrict__ d_out, int n) {
    __shared__ float ssum[4][64];
    __shared__ float smax[4][64];
    int g = blockIdx.x;
    int wave = threadIdx.x >> 6, j = threadIdx.x & 63;
    int lo = 0, hi = n;
    while (lo < hi) { int mid = (lo + hi) >> 1; if (batch[mid] < g) lo = mid + 1; else hi = mid; }
    int start = lo;
    hi = n;
    while (lo < hi) { int mid = (lo + hi) >> 1; if (batch[mid] < g + 1) lo = mid + 1; else hi = mid; }
    int end = lo;

    float sum = 0.f, mx = 0.f;
    for (int i = start + wave; i < end; i += 4) {
        float v = h[(size_t)i * HID + j];
        sum += v;
        mx = fmaxf(mx, v);
    }
    ssum[wave][j] = sum;
    smax[wave][j] = mx;
    __syncthreads();
    if (wave == 0) {
        sum = (ssum[0][j] + ssum[1][j]) + (ssum[2][j] + ssum[3][j]);
        mx = fmaxf(fmaxf(smax[0][j], smax[1][j]), fmaxf(smax[2][j], smax[3][j]));
        float cnt = (float)(end - start);
        float mean = sum / fmaxf(cnt, 1.f);
        float* pooled = d_out + NUM_GRAPHS;
        pooled[(size_t)g * (2 * HID) + j] = mean;
        pooled[(size_t)g * (2 * HID) + HID + j] = mx;
        float c = mean * Wout[j] + mx * Wout[HID + j];
#pragma unroll
        for (int off = 32; off; off >>= 1) c += __shfl_down(c, off);
        if (j == 0) d_out[g] = c + bout[0];
    }
}

// ---------------- launch ----------------

extern "C" void kernel_launch(void* const* d_in, const int* in_sizes, int n_in,
                              void* d_out, int out_size, void* d_ws, size_t ws_size,
                              hipStream_t stream) {
    const float* x    = (const float*)d_in[0];
    const int*   edge = (const int*)d_in[1];
    const int*   batch= (const int*)d_in[2];
    const float* W1 = (const float*)d_in[3];  const float* b1 = (const float*)d_in[4];
    const float* W2 = (const float*)d_in[5];  const float* b2 = (const float*)d_in[6];
    const float* W3 = (const float*)d_in[7];  const float* b3 = (const float*)d_in[8];
    const float* W4 = (const float*)d_in[9];  const float* b4 = (const float*)d_in[10];
    const float* Wout = (const float*)d_in[11]; const float* bout = (const float*)d_in[12];
    float* out = (float*)d_out;

    const int N = N_NODES;
    const int E = in_sizes[1] / 2;
    const int* src = edge;
    const int* dst = edge + E;
    const int chunk = (E + NCHUNK - 1) / NCHUNK;

    char* p = (char*)d_ws;
    auto alloc = [&](size_t bytes) -> char* {
        char* r = p;
        p += (bytes + 255) & ~(size_t)255;
        return r;
    };
    int*      pdeg     = (int*)alloc((size_t)N * 4);
    int*      row_ptr  = (int*)alloc((size_t)(N + 1) * 4);
    int*      partial  = (int*)alloc((size_t)TOTP * 4);
    int*      pincl    = (int*)alloc((size_t)TOTP * 4);
    int*      pbase    = (int*)alloc((size_t)TOTP * 4);
    int*      part_off = (int*)alloc((size_t)(NBUCK + 1) * 4);
    unsigned* part     = (unsigned*)alloc((size_t)1600000 * 4);
    int*      cne      = (int*)alloc((size_t)CNE_MAX * 4);
    float*    dis      = (float*)alloc((size_t)N * 4);
    int*      bsum     = (int*)alloc(128 * 4);
    int*      boff     = (int*)alloc(128 * 4);
    __half*   tmp      = (__half*)alloc((size_t)(N + 1) * HID * 2);
    float*    hA       = (float*)alloc((size_t)N * HID * 4);

    hipMemsetAsync(tmp + (size_t)N * HID, 0, HID * 2, stream);   // zero pad row N

    hist_partial<<<NCHUNK, 256, 0, stream>>>(dst, partial, E, chunk);
    int nbp = (TOTP + 1023) / 1024;
    scan1<<<nbp, 256, 0, stream>>>(partial, pincl, bsum, TOTP);
    scan2<<<1, 128, 0, stream>>>(bsum, boff, nbp);
    scan3p<<<(TOTP + 255) / 256, 256, 0, stream>>>(partial, pincl, boff, pbase, part_off, E);
    partition_edges<<<NCHUNK, 256, 0, stream>>>(src, dst, pbase, part, E, chunk);
    deg_dis<<<NBUCK, 256, 0, stream>>>(part, part_off, pdeg, dis, N);

    int nb = (N + 1023) / 1024;
    scan1<<<nb, 256, 0, stream>>>(pdeg, row_ptr + 1, bsum, N);
    scan2<<<1, 128, 0, stream>>>(bsum, boff, nb);
    scan3<<<(N + 255) / 256, 256, 0, stream>>>(row_ptr, boff, N);
    build_csr<<<NBUCK, 256, 0, stream>>>(part, part_off, row_ptr, cne, N);

    const int AGG_BLOCKS = 2048;
    const int GEMM_BLOCKS = 512;   // 2048 waves, ~3 row-tiles each (amortizes B-frag load)

    gemm_mfma<IN_DIM><<<GEMM_BLOCKS, 256, 0, stream>>>(x, W1, dis, tmp, N);
    aggregate<<<AGG_BLOCKS, 256, 0, stream>>>(tmp, dis, row_ptr, cne, b1, hA, N);
    gemm_mfma<HID><<<GEMM_BLOCKS, 256, 0, stream>>>(hA, W2, dis, tmp, N);
    aggregate<<<AGG_BLOCKS, 256, 0, stream>>>(tmp, dis, row_ptr, cne, b2, hA, N);
    gemm_mfma<HID><<<GEMM_BLOCKS, 256, 0, stream>>>(hA, W3, dis, tmp, N);
    aggregate<<<AGG_BLOCKS, 256, 0, stream>>>(tmp, dis, row_ptr, cne, b3, hA, N);
    gemm_mfma<HID><<<GEMM_BLOCKS, 256, 0, stream>>>(hA, W4, dis, tmp, N);
    aggregate<<<AGG_BLOCKS, 256, 0, stream>>>(tmp, dis, row_ptr, cne, b4, hA, N);

    pool_kernel<<<NUM_GRAPHS, 256, 0, stream>>>(hA, batch, Wout, bout, out, N);
}

// Round 12
// 397.079 us; speedup vs baseline: 1.8358x; 1.0924x over previous
//
#include <hip/hip_runtime.h>
#include <hip/hip_fp16.h>

#define N_NODES 100000
#define IN_DIM 128
#define HID 64
#define NUM_GRAPHS 2048
#define CNE_MAX (1600000 + 7 * N_NODES)   // padded-to-8 CSR upper bound
#define BROWS 128                          // rows per bucket
#define NBUCK ((N_NODES + BROWS - 1) / BROWS)   // 782
#define NCHUNK 128                         // edge chunks (one block each)
#define TOTP (NBUCK * NCHUNK)              // 100096 partial counters
#define CAP 4096                           // LDS staging entries per bucket

typedef _Float16 h8 __attribute__((ext_vector_type(8)));
typedef float f4 __attribute__((ext_vector_type(4)));

// ---------------- build phase (NO per-edge global atomics anywhere) ----------------

__global__ __launch_bounds__(256) void hist_partial(const int* __restrict__ dst,
                                                    int* __restrict__ partial,
                                                    int E, int chunk) {
    __shared__ int lh[NBUCK];
    int t = threadIdx.x, c = blockIdx.x;
    for (int b = t; b < NBUCK; b += 256) lh[b] = 0;
    __syncthreads();
    int lo = c * chunk, hi = min(lo + chunk, E);
    for (int i = lo + t; i < hi; i += 256) atomicAdd(&lh[dst[i] >> 7], 1);
    __syncthreads();
    for (int b = t; b < NBUCK; b += 256) partial[b * NCHUNK + c] = lh[b];
}

// phase 1: per-block (1024 elems) inclusive scan + block sums; pad8 applied when flagged
__global__ void scan1(const int* __restrict__ counts, int* __restrict__ out1,
                      int* __restrict__ bsum, int n, int pad8) {
    __shared__ int s[256];
    int t = threadIdx.x;
    int base = blockIdx.x * 1024 + t * 4;
    int v[4];
#pragma unroll
    for (int i = 0; i < 4; i++) {
        int c = (base + i < n) ? counts[base + i] : 0;
        v[i] = pad8 ? ((c + 7) & ~7) : c;
    }
    int tsum = v[0] + v[1] + v[2] + v[3];
    s[t] = tsum;
    __syncthreads();
    for (int off = 1; off < 256; off <<= 1) {
        int tv = (t >= off) ? s[t - off] : 0;
        __syncthreads();
        s[t] += tv;
        __syncthreads();
    }
    int excl = s[t] - tsum;
    if (t == 255) bsum[blockIdx.x] = s[255];
    int run = excl;
#pragma unroll
    for (int i = 0; i < 4; i++) {
        run += v[i];
        if (base + i < n) out1[base + i] = run;
    }
}

__global__ void scan2(const int* __restrict__ bsum, int* __restrict__ boff, int nb) {
    __shared__ int s[128];
    int t = threadIdx.x;
    int v = (t < nb) ? bsum[t] : 0;
    s[t] = v;
    __syncthreads();
    for (int off = 1; off < 128; off <<= 1) {
        int tv = (t >= off) ? s[t - off] : 0;
        __syncthreads();
        s[t] += tv;
        __syncthreads();
    }
    if (t < nb) boff[t] = s[t] - v;
}

__global__ void scan3(int* __restrict__ row_ptr, const int* __restrict__ boff, int n) {
    int i = blockIdx.x * blockDim.x + threadIdx.x;
    if (i == 0) row_ptr[0] = 0;
    if (i < n) row_ptr[i + 1] += boff[i >> 10];
}

__global__ void scan3p(const int* __restrict__ partial, const int* __restrict__ pincl,
                       const int* __restrict__ boff, int* __restrict__ base,
                       int* __restrict__ part_off, int E) {
    int i = blockIdx.x * blockDim.x + threadIdx.x;
    if (i < TOTP) {
        int v = pincl[i] + boff[i >> 10] - partial[i];
        base[i] = v;
        if ((i & (NCHUNK - 1)) == 0) part_off[i / NCHUNK] = v;
    }
    if (i == 0) part_off[NBUCK] = E;
}

__global__ __launch_bounds__(256) void partition_edges(const int* __restrict__ src,
                                                       const int* __restrict__ dst,
                                                       const int* __restrict__ base,
                                                       unsigned* __restrict__ part,
                                                       int E, int chunk) {
    __shared__ int cur[NBUCK];
    int t = threadIdx.x, c = blockIdx.x;
    for (int b = t; b < NBUCK; b += 256) cur[b] = base[b * NCHUNK + c];
    __syncthreads();
    int lo = c * chunk, hi = min(lo + chunk, E);
    for (int i = lo + t; i < hi; i += 256) {
        int s = src[i], d = dst[i];
        int pos = atomicAdd(&cur[d >> 7], 1);
        part[pos] = (unsigned)s | ((unsigned)(d & (BROWS - 1)) << 17);
    }
}

__global__ __launch_bounds__(256) void deg_dis(const unsigned* __restrict__ part,
                                               const int* __restrict__ part_off,
                                               int* __restrict__ pdeg,
                                               float* __restrict__ dis, int n) {
    __shared__ int cnt[BROWS];
    int t = threadIdx.x, b = blockIdx.x;
    int r0 = b * BROWS;
    if (t < BROWS) cnt[t] = 0;
    __syncthreads();
    for (int i = part_off[b] + t; i < part_off[b + 1]; i += 256)
        atomicAdd(&cnt[part[i] >> 17], 1);
    __syncthreads();
    int nrows = min(BROWS, n - r0);
    if (t < nrows) {
        int dg = cnt[t];
        pdeg[r0 + t] = dg;                          // raw; scan1 applies pad8
        dis[r0 + t] = rsqrtf((float)(dg + 1));
    }
}

__global__ __launch_bounds__(256) void build_csr(const unsigned* __restrict__ part,
                                                 const int* __restrict__ part_off,
                                                 const int* __restrict__ row_ptr,
                                                 int* __restrict__ cne, int n) {
    __shared__ int fill[BROWS];
    __shared__ int stage[CAP];
    int b = blockIdx.x;
    int r0 = b * BROWS;
    int t = threadIdx.x;
    int nrows = min(BROWS, n - r0);
    int base = row_ptr[r0];
    int region = row_ptr[r0 + nrows] - base;
    for (int r = t; r < nrows; r += 256) fill[r] = row_ptr[r0 + r] - base;
    int i0 = part_off[b], i1 = part_off[b + 1];
    if (region <= CAP) {
        for (int i = t; i < region; i += 256) stage[i] = N_NODES;
        __syncthreads();
        for (int i = i0 + t; i < i1; i += 256) {
            unsigned pe = part[i];
            int pos = atomicAdd(&fill[pe >> 17], 1);
            stage[pos] = (int)(pe & 0x1FFFFu);
        }
        __syncthreads();
        for (int i = t; i < region; i += 256) cne[base + i] = stage[i];
    } else {
        for (int i = t; i < region; i += 256) cne[base + i] = N_NODES;
        __syncthreads();
        for (int i = i0 + t; i < i1; i += 256) {
            unsigned pe = part[i];
            int pos = atomicAdd(&fill[pe >> 17], 1);
            cne[base + pos] = (int)(pe & 0x1FFFFu);
        }
    }
}

// ---------------- per-layer compute ----------------

// MFMA GEMM: out[row][col] = (half) dis[row] * sum_k X[row][k] * W[k][col]
// XT = float (layer 1) or _Float16 (h from previous layer; A-frag = direct 16 B load).
// B-fragments built in-register from fp32 W. Layouts verified (R9/R11 + guide m89/m91).
template <int K, typename XT>
__global__ __launch_bounds__(256) void gemm_mfma(const XT* __restrict__ X,
                                                 const float* __restrict__ W,
                                                 const float* __restrict__ dis,
                                                 __half* __restrict__ out, int n) {
    const int KS = K / 32;
    int wave = threadIdx.x >> 6, lane = threadIdx.x & 63;
    int quad = lane >> 4, l16 = lane & 15;
    h8 b[4][KS];
#pragma unroll
    for (int ct = 0; ct < 4; ct++)
#pragma unroll
        for (int ks = 0; ks < KS; ks++)
#pragma unroll
            for (int j = 0; j < 8; j++)
                b[ct][ks][j] = (_Float16)W[(ks * 32 + quad * 8 + j) * HID + ct * 16 + l16];
    int ntile = n >> 4;
    int wpb = blockDim.x >> 6;
    int stride = gridDim.x * wpb;
    for (int rt = blockIdx.x * wpb + wave; rt < ntile; rt += stride) {
        int row0 = rt << 4;
        const XT* xr = X + (size_t)(row0 + l16) * K + quad * 8;
        f4 acc[4];
#pragma unroll
        for (int ct = 0; ct < 4; ct++) acc[ct] = (f4)(0.f);
#pragma unroll
        for (int ks = 0; ks < KS; ks++) {
            h8 a;
            if constexpr (__is_same(XT, float)) {
                float4 xa = *(const float4*)(xr + ks * 32);
                float4 xb = *(const float4*)(xr + ks * 32 + 4);
                a[0] = (_Float16)xa.x; a[1] = (_Float16)xa.y;
                a[2] = (_Float16)xa.z; a[3] = (_Float16)xa.w;
                a[4] = (_Float16)xb.x; a[5] = (_Float16)xb.y;
                a[6] = (_Float16)xb.z; a[7] = (_Float16)xb.w;
            } else {
                a = *(const h8*)(xr + ks * 32);
            }
#pragma unroll
            for (int ct = 0; ct < 4; ct++)
                acc[ct] = __builtin_amdgcn_mfma_f32_16x16x32_f16(a, b[ct][ks], acc[ct], 0, 0, 0);
        }
        int r0 = row0 + quad * 4;
        float4 dv = *(const float4*)(dis + r0);
        float dd[4] = {dv.x, dv.y, dv.z, dv.w};
#pragma unroll
        for (int reg = 0; reg < 4; reg++) {
            __half* orow = out + (size_t)(r0 + reg) * HID + l16;
            orow[0]  = __float2half(dd[reg] * acc[0][reg]);
            orow[16] = __float2half(dd[reg] * acc[1][reg]);
            orow[32] = __float2half(dd[reg] * acc[2][reg]);
            orow[48] = __float2half(dd[reg] * acc[3][reg]);
        }
    }
}

// out[row] = relu( dis[row] * (tmp2[row] + sum_cols tmp2[col]) + bias ); pads read zero row N.
// Rows padded to 8; 8 gathers in flight + indices prefetched one group ahead.
// OutT = __half (interior layers, numerically identical to casting in gemm) or float (last).
template <typename OutT>
__global__ __launch_bounds__(256) void aggregate(const __half* __restrict__ tmp,
                                                 const float* __restrict__ dis,
                                                 const int* __restrict__ row_ptr,
                                                 const int* __restrict__ cne,
                                                 const float* __restrict__ bias,
                                                 OutT* __restrict__ out, int n) {
    int wave = threadIdx.x >> 6, lane = threadIdx.x & 63;
    int wpb = blockDim.x >> 6;
    int stride = gridDim.x * wpb;
    float bl = bias[lane];
    for (int row = blockIdx.x * wpb + wave; row < n; row += stride) {
        float dr = dis[row];
        float a0 = __half2float(tmp[row * HID + lane]);   // self-loop
        float a1 = 0.f, a2 = 0.f, a3 = 0.f, a4 = 0.f, a5 = 0.f, a6 = 0.f, a7 = 0.f;
        int s = row_ptr[row], e = row_ptr[row + 1];
        if (s < e) {
            int4 ia0 = *(const int4*)(cne + s);
            int4 ia1 = *(const int4*)(cne + s + 4);
            float v0 = __half2float(tmp[ia0.x * HID + lane]);
            float v1 = __half2float(tmp[ia0.y * HID + lane]);
            float v2 = __half2float(tmp[ia0.z * HID + lane]);
            float v3 = __half2float(tmp[ia0.w * HID + lane]);
            float v4 = __half2float(tmp[ia1.x * HID + lane]);
            float v5 = __half2float(tmp[ia1.y * HID + lane]);
            float v6 = __half2float(tmp[ia1.z * HID + lane]);
            float v7 = __half2float(tmp[ia1.w * HID + lane]);
            int4 ib0, ib1;
            if (s + 8 < e) {
                ib0 = *(const int4*)(cne + s + 8);
                ib1 = *(const int4*)(cne + s + 12);
            }
            for (int t = s + 8; t < e; t += 8) {
                // gathers for group b (indices arrived one iteration ago)
                float u0 = __half2float(tmp[ib0.x * HID + lane]);
                float u1 = __half2float(tmp[ib0.y * HID + lane]);
                float u2 = __half2float(tmp[ib0.z * HID + lane]);
                float u3 = __half2float(tmp[ib0.w * HID + lane]);
                float u4 = __half2float(tmp[ib1.x * HID + lane]);
                float u5 = __half2float(tmp[ib1.y * HID + lane]);
                float u6 = __half2float(tmp[ib1.z * HID + lane]);
                float u7 = __half2float(tmp[ib1.w * HID + lane]);
                // prefetch indices for the group after b
                if (t + 8 < e) {
                    ib0 = *(const int4*)(cne + t + 8);
                    ib1 = *(const int4*)(cne + t + 12);
                }
                // accumulate group a (in flight since last iteration)
                a0 += v0; a1 += v1; a2 += v2; a3 += v3;
                a4 += v4; a5 += v5; a6 += v6; a7 += v7;
                v0 = u0; v1 = u1; v2 = u2; v3 = u3;
                v4 = u4; v5 = u5; v6 = u6; v7 = u7;
            }
            a0 += v0; a1 += v1; a2 += v2; a3 += v3;
            a4 += v4; a5 += v5; a6 += v6; a7 += v7;
        }
        float r = dr * (((a0 + a1) + (a2 + a3)) + ((a4 + a5) + (a6 + a7))) + bl;
        r = fmaxf(r, 0.f);
        if constexpr (__is_same(OutT, __half))
            out[row * HID + lane] = __float2half(r);
        else
            out[row * HID + lane] = r;
    }
}

__global__ __launch_bounds__(256) void pool_kernel(const float* __restrict__ h,
                                                   const int* __restrict__ batch,
                                                   const float* __restrict__ Wout,
                                                   const float* __restrict__ bout,
                                                   float* __restrict__ d_out, int n) {
    __shared__ float ssum[4][64];
    __shared__ float smax[4][64];
    int g = blockIdx.x;
    int wave = threadIdx.x >> 6, j = threadIdx.x & 63;
    int lo = 0, hi = n;
    while (lo < hi) { int mid = (lo + hi) >> 1; if (batch[mid] < g) lo = mid + 1; else hi = mid; }
    int start = lo;
    hi = n;
    while (lo < hi) { int mid = (lo + hi) >> 1; if (batch[mid] < g + 1) lo = mid + 1; else hi = mid; }
    int end = lo;

    float sum = 0.f, mx = 0.f;
    for (int i = start + wave; i < end; i += 4) {
        float v = h[(size_t)i * HID + j];
        sum += v;
        mx = fmaxf(mx, v);
    }
    ssum[wave][j] = sum;
    smax[wave][j] = mx;
    __syncthreads();
    if (wave == 0) {
        sum = (ssum[0][j] + ssum[1][j]) + (ssum[2][j] + ssum[3][j]);
        mx = fmaxf(fmaxf(smax[0][j], smax[1][j]), fmaxf(smax[2][j], smax[3][j]));
        float cnt = (float)(end - start);
        float mean = sum / fmaxf(cnt, 1.f);
        float* pooled = d_out + NUM_GRAPHS;
        pooled[(size_t)g * (2 * HID) + j] = mean;
        pooled[(size_t)g * (2 * HID) + HID + j] = mx;
        float c = mean * Wout[j] + mx * Wout[HID + j];
#pragma unroll
        for (int off = 32; off; off >>= 1) c += __shfl_down(c, off);
        if (j == 0) d_out[g] = c + bout[0];
    }
}

// ---------------- launch ----------------

extern "C" void kernel_launch(void* const* d_in, const int* in_sizes, int n_in,
                              void* d_out, int out_size, void* d_ws, size_t ws_size,
                              hipStream_t stream) {
    const float* x    = (const float*)d_in[0];
    const int*   edge = (const int*)d_in[1];
    const int*   batch= (const int*)d_in[2];
    const float* W1 = (const float*)d_in[3];  const float* b1 = (const float*)d_in[4];
    const float* W2 = (const float*)d_in[5];  const float* b2 = (const float*)d_in[6];
    const float* W3 = (const float*)d_in[7];  const float* b3 = (const float*)d_in[8];
    const float* W4 = (const float*)d_in[9];  const float* b4 = (const float*)d_in[10];
    const float* Wout = (const float*)d_in[11]; const float* bout = (const float*)d_in[12];
    float* out = (float*)d_out;

    const int N = N_NODES;
    const int E = in_sizes[1] / 2;
    const int* src = edge;
    const int* dst = edge + E;
    const int chunk = (E + NCHUNK - 1) / NCHUNK;

    char* p = (char*)d_ws;
    auto alloc = [&](size_t bytes) -> char* {
        char* r = p;
        p += (bytes + 255) & ~(size_t)255;
        return r;
    };
    int*      pdeg     = (int*)alloc((size_t)N * 4);
    int*      row_ptr  = (int*)alloc((size_t)(N + 1) * 4);
    int*      partial  = (int*)alloc((size_t)TOTP * 4);
    int*      pincl    = (int*)alloc((size_t)TOTP * 4);
    int*      pbase    = (int*)alloc((size_t)TOTP * 4);
    int*      part_off = (int*)alloc((size_t)(NBUCK + 1) * 4);
    unsigned* part     = (unsigned*)alloc((size_t)1600000 * 4);
    int*      cne      = (int*)alloc((size_t)CNE_MAX * 4);
    float*    dis      = (float*)alloc((size_t)N * 4);
    int*      bsum     = (int*)alloc(128 * 4);
    int*      boff     = (int*)alloc(128 * 4);
    __half*   tmp      = (__half*)alloc((size_t)(N + 1) * HID * 2);
    float*    hA       = (float*)alloc((size_t)N * HID * 4);
    __half*   hH       = (__half*)hA;   // fp16 h aliases front of hA (hA dead until agg4)

    hipMemsetAsync(tmp + (size_t)N * HID, 0, HID * 2, stream);   // zero pad row N

    hist_partial<<<NCHUNK, 256, 0, stream>>>(dst, partial, E, chunk);
    int nbp = (TOTP + 1023) / 1024;
    scan1<<<nbp, 256, 0, stream>>>(partial, pincl, bsum, TOTP, 0);
    scan2<<<1, 128, 0, stream>>>(bsum, boff, nbp);
    scan3p<<<(TOTP + 255) / 256, 256, 0, stream>>>(partial, pincl, boff, pbase, part_off, E);
    partition_edges<<<NCHUNK, 256, 0, stream>>>(src, dst, pbase, part, E, chunk);
    deg_dis<<<NBUCK, 256, 0, stream>>>(part, part_off, pdeg, dis, N);

    int nb = (N + 1023) / 1024;
    scan1<<<nb, 256, 0, stream>>>(pdeg, row_ptr + 1, bsum, N, 1);
    scan2<<<1, 128, 0, stream>>>(bsum, boff, nb);
    scan3<<<(N + 255) / 256, 256, 0, stream>>>(row_ptr, boff, N);
    build_csr<<<NBUCK, 256, 0, stream>>>(part, part_off, row_ptr, cne, N);

    const int AGG_BLOCKS = 2048;
    const int GEMM_BLOCKS = 1024;

    gemm_mfma<IN_DIM, float><<<GEMM_BLOCKS, 256, 0, stream>>>(x, W1, dis, tmp, N);
    aggregate<__half><<<AGG_BLOCKS, 256, 0, stream>>>(tmp, dis, row_ptr, cne, b1, hH, N);
    gemm_mfma<HID, _Float16><<<GEMM_BLOCKS, 256, 0, stream>>>((_Float16*)hH, W2, dis, tmp, N);
    aggregate<__half><<<AGG_BLOCKS, 256, 0, stream>>>(tmp, dis, row_ptr, cne, b2, hH, N);
    gemm_mfma<HID, _Float16><<<GEMM_BLOCKS, 256, 0, stream>>>((_Float16*)hH, W3, dis, tmp, N);
    aggregate<__half><<<AGG_BLOCKS, 256, 0, stream>>>(tmp, dis, row_ptr, cne, b3, hH, N);
    gemm_mfma<HID, _Float16><<<GEMM_BLOCKS, 256, 0, stream>>>((_Float16*)hH, W4, dis, tmp, N);
    aggregate<float><<<AGG_BLOCKS, 256, 0, stream>>>(tmp, dis, row_ptr, cne, b4, hA, N);

    pool_kernel<<<NUM_GRAPHS, 256, 0, stream>>>(hA, batch, Wout, bout, out, N);
}

// Round 13
// 377.876 us; speedup vs baseline: 1.9291x; 1.0508x over previous
//
#include <hip/hip_runtime.h>
#include <hip/hip_fp16.h>

#define N_NODES 100000
#define IN_DIM 128
#define HID 64
#define NUM_GRAPHS 2048
#define CNE_MAX (1600000 + 7 * N_NODES)   // padded-to-8 CSR upper bound
#define BROWS 128                          // rows per bucket
#define NBUCK ((N_NODES + BROWS - 1) / BROWS)   // 782
#define NCHUNK 256                         // edge chunks (one block each)
#define TOTP (NBUCK * NCHUNK)              // 200192 partial counters
#define CAP 4096                           // LDS staging entries per bucket

typedef _Float16 h8 __attribute__((ext_vector_type(8)));
typedef float f4 __attribute__((ext_vector_type(4)));

// ---------------- build phase (NO per-edge global atomics anywhere) ----------------

__global__ __launch_bounds__(256) void hist_partial(const int* __restrict__ dst,
                                                    int* __restrict__ partial,
                                                    int E, int chunk) {
    __shared__ int lh[NBUCK];
    int t = threadIdx.x, c = blockIdx.x;
    for (int b = t; b < NBUCK; b += 256) lh[b] = 0;
    __syncthreads();
    int lo = c * chunk, hi = min(lo + chunk, E);
    for (int i = lo + t; i < hi; i += 256) atomicAdd(&lh[dst[i] >> 7], 1);
    __syncthreads();
    for (int b = t; b < NBUCK; b += 256) partial[b * NCHUNK + c] = lh[b];
}

// phase 1: per-block (1024 elems) inclusive scan + block sums; pad8 applied when flagged
__global__ void scan1(const int* __restrict__ counts, int* __restrict__ out1,
                      int* __restrict__ bsum, int n, int pad8) {
    __shared__ int s[256];
    int t = threadIdx.x;
    int base = blockIdx.x * 1024 + t * 4;
    int v[4];
#pragma unroll
    for (int i = 0; i < 4; i++) {
        int c = (base + i < n) ? counts[base + i] : 0;
        v[i] = pad8 ? ((c + 7) & ~7) : c;
    }
    int tsum = v[0] + v[1] + v[2] + v[3];
    s[t] = tsum;
    __syncthreads();
    for (int off = 1; off < 256; off <<= 1) {
        int tv = (t >= off) ? s[t - off] : 0;
        __syncthreads();
        s[t] += tv;
        __syncthreads();
    }
    int excl = s[t] - tsum;
    if (t == 255) bsum[blockIdx.x] = s[255];
    int run = excl;
#pragma unroll
    for (int i = 0; i < 4; i++) {
        run += v[i];
        if (base + i < n) out1[base + i] = run;
    }
}

// phase 2: exclusive scan of block sums (nb <= 256)
__global__ void scan2(const int* __restrict__ bsum, int* __restrict__ boff, int nb) {
    __shared__ int s[256];
    int t = threadIdx.x;
    int v = (t < nb) ? bsum[t] : 0;
    s[t] = v;
    __syncthreads();
    for (int off = 1; off < 256; off <<= 1) {
        int tv = (t >= off) ? s[t - off] : 0;
        __syncthreads();
        s[t] += tv;
        __syncthreads();
    }
    if (t < nb) boff[t] = s[t] - v;
}

__global__ void scan3(int* __restrict__ row_ptr, const int* __restrict__ boff, int n) {
    int i = blockIdx.x * blockDim.x + threadIdx.x;
    if (i == 0) row_ptr[0] = 0;
    if (i < n) row_ptr[i + 1] += boff[i >> 10];
}

__global__ void scan3p(const int* __restrict__ partial, const int* __restrict__ pincl,
                       const int* __restrict__ boff, int* __restrict__ base,
                       int* __restrict__ part_off, int E) {
    int i = blockIdx.x * blockDim.x + threadIdx.x;
    if (i < TOTP) {
        int v = pincl[i] + boff[i >> 10] - partial[i];
        base[i] = v;
        if ((i & (NCHUNK - 1)) == 0) part_off[i / NCHUNK] = v;
    }
    if (i == 0) part_off[NBUCK] = E;
}

__global__ __launch_bounds__(256) void partition_edges(const int* __restrict__ src,
                                                       const int* __restrict__ dst,
                                                       const int* __restrict__ base,
                                                       unsigned* __restrict__ part,
                                                       int E, int chunk) {
    __shared__ int cur[NBUCK];
    int t = threadIdx.x, c = blockIdx.x;
    for (int b = t; b < NBUCK; b += 256) cur[b] = base[b * NCHUNK + c];
    __syncthreads();
    int lo = c * chunk, hi = min(lo + chunk, E);
    for (int i = lo + t; i < hi; i += 256) {
        int s = src[i], d = dst[i];
        int pos = atomicAdd(&cur[d >> 7], 1);
        part[pos] = (unsigned)s | ((unsigned)(d & (BROWS - 1)) << 17);
    }
}

__global__ __launch_bounds__(256) void deg_dis(const unsigned* __restrict__ part,
                                               const int* __restrict__ part_off,
                                               int* __restrict__ pdeg,
                                               float* __restrict__ dis, int n) {
    __shared__ int cnt[BROWS];
    int t = threadIdx.x, b = blockIdx.x;
    int r0 = b * BROWS;
    if (t < BROWS) cnt[t] = 0;
    __syncthreads();
    for (int i = part_off[b] + t; i < part_off[b + 1]; i += 256)
        atomicAdd(&cnt[part[i] >> 17], 1);
    __syncthreads();
    int nrows = min(BROWS, n - r0);
    if (t < nrows) {
        int dg = cnt[t];
        pdeg[r0 + t] = dg;                          // raw; scan1 applies pad8
        dis[r0 + t] = rsqrtf((float)(dg + 1));
    }
}

__global__ __launch_bounds__(256) void build_csr(const unsigned* __restrict__ part,
                                                 const int* __restrict__ part_off,
                                                 const int* __restrict__ row_ptr,
                                                 int* __restrict__ cne, int n) {
    __shared__ int fill[BROWS];
    __shared__ int stage[CAP];
    int b = blockIdx.x;
    int r0 = b * BROWS;
    int t = threadIdx.x;
    int nrows = min(BROWS, n - r0);
    int base = row_ptr[r0];
    int region = row_ptr[r0 + nrows] - base;
    for (int r = t; r < nrows; r += 256) fill[r] = row_ptr[r0 + r] - base;
    int i0 = part_off[b], i1 = part_off[b + 1];
    if (region <= CAP) {
        for (int i = t; i < region; i += 256) stage[i] = N_NODES;
        __syncthreads();
        for (int i = i0 + t; i < i1; i += 256) {
            unsigned pe = part[i];
            int pos = atomicAdd(&fill[pe >> 17], 1);
            stage[pos] = (int)(pe & 0x1FFFFu);
        }
        __syncthreads();
        for (int i = t; i < region; i += 256) cne[base + i] = stage[i];
    } else {
        for (int i = t; i < region; i += 256) cne[base + i] = N_NODES;
        __syncthreads();
        for (int i = i0 + t; i < i1; i += 256) {
            unsigned pe = part[i];
            int pos = atomicAdd(&fill[pe >> 17], 1);
            cne[base + pos] = (int)(pe & 0x1FFFFu);
        }
    }
}

// ---------------- per-layer compute ----------------

// MFMA GEMM: out[row][col] = (half) dis[row] * sum_k X[row][k] * W[k][col]
// XT = float (layer 1) or _Float16 (h from previous layer; A-frag = direct 16 B load).
// B-fragments built in-register from fp32 W. Layouts verified (R11/R12 + guide m89/m91).
template <int K, typename XT>
__global__ __launch_bounds__(256) void gemm_mfma(const XT* __restrict__ X,
                                                 const float* __restrict__ W,
                                                 const float* __restrict__ dis,
                                                 __half* __restrict__ out, int n) {
    const int KS = K / 32;
    int wave = threadIdx.x >> 6, lane = threadIdx.x & 63;
    int quad = lane >> 4, l16 = lane & 15;
    h8 b[4][KS];
#pragma unroll
    for (int ct = 0; ct < 4; ct++)
#pragma unroll
        for (int ks = 0; ks < KS; ks++)
#pragma unroll
            for (int j = 0; j < 8; j++)
                b[ct][ks][j] = (_Float16)W[(ks * 32 + quad * 8 + j) * HID + ct * 16 + l16];
    int ntile = n >> 4;
    int wpb = blockDim.x >> 6;
    int stride = gridDim.x * wpb;
    for (int rt = blockIdx.x * wpb + wave; rt < ntile; rt += stride) {
        int row0 = rt << 4;
        const XT* xr = X + (size_t)(row0 + l16) * K + quad * 8;
        f4 acc[4];
#pragma unroll
        for (int ct = 0; ct < 4; ct++) acc[ct] = (f4)(0.f);
#pragma unroll
        for (int ks = 0; ks < KS; ks++) {
            h8 a;
            if constexpr (__is_same(XT, float)) {
                float4 xa = *(const float4*)(xr + ks * 32);
                float4 xb = *(const float4*)(xr + ks * 32 + 4);
                a[0] = (_Float16)xa.x; a[1] = (_Float16)xa.y;
                a[2] = (_Float16)xa.z; a[3] = (_Float16)xa.w;
                a[4] = (_Float16)xb.x; a[5] = (_Float16)xb.y;
                a[6] = (_Float16)xb.z; a[7] = (_Float16)xb.w;
            } else {
                a = *(const h8*)(xr + ks * 32);
            }
#pragma unroll
            for (int ct = 0; ct < 4; ct++)
                acc[ct] = __builtin_amdgcn_mfma_f32_16x16x32_f16(a, b[ct][ks], acc[ct], 0, 0, 0);
        }
        int r0 = row0 + quad * 4;
        float4 dv = *(const float4*)(dis + r0);
        float dd[4] = {dv.x, dv.y, dv.z, dv.w};
#pragma unroll
        for (int reg = 0; reg < 4; reg++) {
            __half* orow = out + (size_t)(r0 + reg) * HID + l16;
            orow[0]  = __float2half(dd[reg] * acc[0][reg]);
            orow[16] = __float2half(dd[reg] * acc[1][reg]);
            orow[32] = __float2half(dd[reg] * acc[2][reg]);
            orow[48] = __float2half(dd[reg] * acc[3][reg]);
        }
    }
}

// out[row] = relu( dis[row] * (tmp2[row] + sum_cols tmp2[col]) + bias ); pads read zero row N.
// half2 pairing: lane l -> column pair (2m,2m+1), m=l&31; wave halves (hh=l>>5) take
// alternating edges of each pair via cndmask -> one dword load serves 2 edges.
// shfl_xor(32) combines halves; self-loop added post-reduction; idx-prefetch pipeline kept.
template <typename OutT>
__global__ __launch_bounds__(256) void aggregate(const __half* __restrict__ tmp,
                                                 const float* __restrict__ dis,
                                                 const int* __restrict__ row_ptr,
                                                 const int* __restrict__ cne,
                                                 const float* __restrict__ bias,
                                                 OutT* __restrict__ out, int n) {
    int wave = threadIdx.x >> 6, lane = threadIdx.x & 63;
    int m = lane & 31, hh = lane >> 5;
    int wpb = blockDim.x >> 6;
    int stride = gridDim.x * wpb;
    float2 blv = *(const float2*)(bias + 2 * m);
    for (int row = blockIdx.x * wpb + wave; row < n; row += stride) {
        float dr = dis[row];
        float2 a0 = {0.f, 0.f}, a1 = {0.f, 0.f}, a2 = {0.f, 0.f}, a3 = {0.f, 0.f};
        int s = row_ptr[row], e = row_ptr[row + 1];
        if (s < e) {
            int4 i0 = *(const int4*)(cne + s);
            int4 i1 = *(const int4*)(cne + s + 4);
            int c0 = hh ? i0.y : i0.x;
            int c1 = hh ? i0.w : i0.z;
            int c2 = hh ? i1.y : i1.x;
            int c3 = hh ? i1.w : i1.z;
            __half2 g0 = *(const __half2*)(tmp + c0 * HID + 2 * m);
            __half2 g1 = *(const __half2*)(tmp + c1 * HID + 2 * m);
            __half2 g2 = *(const __half2*)(tmp + c2 * HID + 2 * m);
            __half2 g3 = *(const __half2*)(tmp + c3 * HID + 2 * m);
            int4 ni0, ni1;
            if (s + 8 < e) {
                ni0 = *(const int4*)(cne + s + 8);
                ni1 = *(const int4*)(cne + s + 12);
            }
            for (int t = s + 8; t < e; t += 8) {
                int d0 = hh ? ni0.y : ni0.x;
                int d1 = hh ? ni0.w : ni0.z;
                int d2 = hh ? ni1.y : ni1.x;
                int d3 = hh ? ni1.w : ni1.z;
                __half2 u0 = *(const __half2*)(tmp + d0 * HID + 2 * m);
                __half2 u1 = *(const __half2*)(tmp + d1 * HID + 2 * m);
                __half2 u2 = *(const __half2*)(tmp + d2 * HID + 2 * m);
                __half2 u3 = *(const __half2*)(tmp + d3 * HID + 2 * m);
                if (t + 8 < e) {
                    ni0 = *(const int4*)(cne + t + 8);
                    ni1 = *(const int4*)(cne + t + 12);
                }
                float2 f0 = __half22float2(g0), f1 = __half22float2(g1);
                float2 f2 = __half22float2(g2), f3 = __half22float2(g3);
                a0.x += f0.x; a0.y += f0.y;
                a1.x += f1.x; a1.y += f1.y;
                a2.x += f2.x; a2.y += f2.y;
                a3.x += f3.x; a3.y += f3.y;
                g0 = u0; g1 = u1; g2 = u2; g3 = u3;
            }
            float2 f0 = __half22float2(g0), f1 = __half22float2(g1);
            float2 f2 = __half22float2(g2), f3 = __half22float2(g3);
            a0.x += f0.x; a0.y += f0.y;
            a1.x += f1.x; a1.y += f1.y;
            a2.x += f2.x; a2.y += f2.y;
            a3.x += f3.x; a3.y += f3.y;
        }
        float sx = (a0.x + a1.x) + (a2.x + a3.x);
        float sy = (a0.y + a1.y) + (a2.y + a3.y);
        sx += __shfl_xor(sx, 32);
        sy += __shfl_xor(sy, 32);
        float2 selff = __half22float2(*(const __half2*)(tmp + row * HID + 2 * m));
        float rx = fmaxf(dr * (selff.x + sx) + blv.x, 0.f);
        float ry = fmaxf(dr * (selff.y + sy) + blv.y, 0.f);
        if (hh == 0) {
            if constexpr (__is_same(OutT, __half)) {
                *(__half2*)(out + row * HID + 2 * m) = __floats2half2_rn(rx, ry);
            } else {
                *(float2*)(out + row * HID + 2 * m) = make_float2(rx, ry);
            }
        }
    }
}

__global__ __launch_bounds__(256) void pool_kernel(const float* __restrict__ h,
                                                   const int* __restrict__ batch,
                                                   const float* __restrict__ Wout,
                                                   const float* __restrict__ bout,
                                                   float* __restrict__ d_out, int n) {
    __shared__ float ssum[4][64];
    __shared__ float smax[4][64];
    int g = blockIdx.x;
    int wave = threadIdx.x >> 6, j = threadIdx.x & 63;
    int lo = 0, hi = n;
    while (lo < hi) { int mid = (lo + hi) >> 1; if (batch[mid] < g) lo = mid + 1; else hi = mid; }
    int start = lo;
    hi = n;
    while (lo < hi) { int mid = (lo + hi) >> 1; if (batch[mid] < g + 1) lo = mid + 1; else hi = mid; }
    int end = lo;

    float sum = 0.f, mx = 0.f;
    for (int i = start + wave; i < end; i += 4) {
        float v = h[(size_t)i * HID + j];
        sum += v;
        mx = fmaxf(mx, v);
    }
    ssum[wave][j] = sum;
    smax[wave][j] = mx;
    __syncthreads();
    if (wave == 0) {
        sum = (ssum[0][j] + ssum[1][j]) + (ssum[2][j] + ssum[3][j]);
        mx = fmaxf(fmaxf(smax[0][j], smax[1][j]), fmaxf(smax[2][j], smax[3][j]));
        float cnt = (float)(end - start);
        float mean = sum / fmaxf(cnt, 1.f);
        float* pooled = d_out + NUM_GRAPHS;
        pooled[(size_t)g * (2 * HID) + j] = mean;
        pooled[(size_t)g * (2 * HID) + HID + j] = mx;
        float c = mean * Wout[j] + mx * Wout[HID + j];
#pragma unroll
        for (int off = 32; off; off >>= 1) c += __shfl_down(c, off);
        if (j == 0) d_out[g] = c + bout[0];
    }
}

// ---------------- launch ----------------

extern "C" void kernel_launch(void* const* d_in, const int* in_sizes, int n_in,
                              void* d_out, int out_size, void* d_ws, size_t ws_size,
                              hipStream_t stream) {
    const float* x    = (const float*)d_in[0];
    const int*   edge = (const int*)d_in[1];
    const int*   batch= (const int*)d_in[2];
    const float* W1 = (const float*)d_in[3];  const float* b1 = (const float*)d_in[4];
    const float* W2 = (const float*)d_in[5];  const float* b2 = (const float*)d_in[6];
    const float* W3 = (const float*)d_in[7];  const float* b3 = (const float*)d_in[8];
    const float* W4 = (const float*)d_in[9];  const float* b4 = (const float*)d_in[10];
    const float* Wout = (const float*)d_in[11]; const float* bout = (const float*)d_in[12];
    float* out = (float*)d_out;

    const int N = N_NODES;
    const int E = in_sizes[1] / 2;
    const int* src = edge;
    const int* dst = edge + E;
    const int chunk = (E + NCHUNK - 1) / NCHUNK;

    char* p = (char*)d_ws;
    auto alloc = [&](size_t bytes) -> char* {
        char* r = p;
        p += (bytes + 255) & ~(size_t)255;
        return r;
    };
    int*      pdeg     = (int*)alloc((size_t)N * 4);
    int*      row_ptr  = (int*)alloc((size_t)(N + 1) * 4);
    int*      partial  = (int*)alloc((size_t)TOTP * 4);
    int*      pincl    = (int*)alloc((size_t)TOTP * 4);
    int*      pbase    = (int*)alloc((size_t)TOTP * 4);
    int*      part_off = (int*)alloc((size_t)(NBUCK + 1) * 4);
    unsigned* part     = (unsigned*)alloc((size_t)1600000 * 4);
    int*      cne      = (int*)alloc((size_t)CNE_MAX * 4);
    float*    dis      = (float*)alloc((size_t)N * 4);
    int*      bsum     = (int*)alloc(256 * 4);
    int*      boff     = (int*)alloc(256 * 4);
    __half*   tmp      = (__half*)alloc((size_t)(N + 1) * HID * 2);
    float*    hA       = (float*)alloc((size_t)N * HID * 4);
    __half*   hH       = (__half*)hA;   // fp16 h aliases front of hA (hA dead until agg4)

    hipMemsetAsync(tmp + (size_t)N * HID, 0, HID * 2, stream);   // zero pad row N

    hist_partial<<<NCHUNK, 256, 0, stream>>>(dst, partial, E, chunk);
    int nbp = (TOTP + 1023) / 1024;   // 196
    scan1<<<nbp, 256, 0, stream>>>(partial, pincl, bsum, TOTP, 0);
    scan2<<<1, 256, 0, stream>>>(bsum, boff, nbp);
    scan3p<<<(TOTP + 255) / 256, 256, 0, stream>>>(partial, pincl, boff, pbase, part_off, E);
    partition_edges<<<NCHUNK, 256, 0, stream>>>(src, dst, pbase, part, E, chunk);
    deg_dis<<<NBUCK, 256, 0, stream>>>(part, part_off, pdeg, dis, N);

    int nb = (N + 1023) / 1024;   // 98
    scan1<<<nb, 256, 0, stream>>>(pdeg, row_ptr + 1, bsum, N, 1);
    scan2<<<1, 256, 0, stream>>>(bsum, boff, nb);
    scan3<<<(N + 255) / 256, 256, 0, stream>>>(row_ptr, boff, N);
    build_csr<<<NBUCK, 256, 0, stream>>>(part, part_off, row_ptr, cne, N);

    const int AGG_BLOCKS = 2048;
    const int GEMM_BLOCKS = 1024;

    gemm_mfma<IN_DIM, float><<<GEMM_BLOCKS, 256, 0, stream>>>(x, W1, dis, tmp, N);
    aggregate<__half><<<AGG_BLOCKS, 256, 0, stream>>>(tmp, dis, row_ptr, cne, b1, hH, N);
    gemm_mfma<HID, _Float16><<<GEMM_BLOCKS, 256, 0, stream>>>((_Float16*)hH, W2, dis, tmp, N);
    aggregate<__half><<<AGG_BLOCKS, 256, 0, stream>>>(tmp, dis, row_ptr, cne, b2, hH, N);
    gemm_mfma<HID, _Float16><<<GEMM_BLOCKS, 256, 0, stream>>>((_Float16*)hH, W3, dis, tmp, N);
    aggregate<__half><<<AGG_BLOCKS, 256, 0, stream>>>(tmp, dis, row_ptr, cne, b3, hH, N);
    gemm_mfma<HID, _Float16><<<GEMM_BLOCKS, 256, 0, stream>>>((_Float16*)hH, W4, dis, tmp, N);
    aggregate<float><<<AGG_BLOCKS, 256, 0, stream>>>(tmp, dis, row_ptr, cne, b4, hA, N);

    pool_kernel<<<NUM_GRAPHS, 256, 0, stream>>>(hA, batch, Wout, bout, out, N);
}

// Round 14
// 357.498 us; speedup vs baseline: 2.0391x; 1.0570x over previous
//
#include <hip/hip_runtime.h>
#include <hip/hip_fp16.h>

#define N_NODES 100000
#define IN_DIM 128
#define HID 64
#define NUM_GRAPHS 2048
#define CNE_MAX (1600000 + 7 * N_NODES)   // padded-to-8 CSR upper bound
#define BROWS 128                          // rows per bucket
#define NBUCK ((N_NODES + BROWS - 1) / BROWS)   // 782
#define NCHUNK 256                         // edge chunks (one block each)
#define TOTP (NBUCK * NCHUNK)              // 200192 partial counters
#define CAP 4096                           // LDS staging entries per bucket

typedef _Float16 h8 __attribute__((ext_vector_type(8)));
typedef float f4 __attribute__((ext_vector_type(4)));

// ---------------- build phase (NO per-edge global atomics anywhere) ----------------

__global__ __launch_bounds__(256) void hist_partial(const int* __restrict__ dst,
                                                    int* __restrict__ partial,
                                                    int E, int chunk) {
    __shared__ int lh[NBUCK];
    int t = threadIdx.x, c = blockIdx.x;
    for (int b = t; b < NBUCK; b += 256) lh[b] = 0;
    __syncthreads();
    int lo = c * chunk, hi = min(lo + chunk, E);
    for (int i = lo + t; i < hi; i += 256) atomicAdd(&lh[dst[i] >> 7], 1);
    __syncthreads();
    for (int b = t; b < NBUCK; b += 256) partial[b * NCHUNK + c] = lh[b];
}

// phase 1: per-block (1024 elems) inclusive scan + block sums; pad8 applied when flagged
__global__ void scan1(const int* __restrict__ counts, int* __restrict__ out1,
                      int* __restrict__ bsum, int n, int pad8) {
    __shared__ int s[256];
    int t = threadIdx.x;
    int base = blockIdx.x * 1024 + t * 4;
    int v[4];
#pragma unroll
    for (int i = 0; i < 4; i++) {
        int c = (base + i < n) ? counts[base + i] : 0;
        v[i] = pad8 ? ((c + 7) & ~7) : c;
    }
    int tsum = v[0] + v[1] + v[2] + v[3];
    s[t] = tsum;
    __syncthreads();
    for (int off = 1; off < 256; off <<= 1) {
        int tv = (t >= off) ? s[t - off] : 0;
        __syncthreads();
        s[t] += tv;
        __syncthreads();
    }
    int excl = s[t] - tsum;
    if (t == 255) bsum[blockIdx.x] = s[255];
    int run = excl;
#pragma unroll
    for (int i = 0; i < 4; i++) {
        run += v[i];
        if (base + i < n) out1[base + i] = run;
    }
}

// phase 2: exclusive scan of block sums (nb <= 256)
__global__ void scan2(const int* __restrict__ bsum, int* __restrict__ boff, int nb) {
    __shared__ int s[256];
    int t = threadIdx.x;
    int v = (t < nb) ? bsum[t] : 0;
    s[t] = v;
    __syncthreads();
    for (int off = 1; off < 256; off <<= 1) {
        int tv = (t >= off) ? s[t - off] : 0;
        __syncthreads();
        s[t] += tv;
        __syncthreads();
    }
    if (t < nb) boff[t] = s[t] - v;
}

__global__ void scan3(int* __restrict__ row_ptr, const int* __restrict__ boff, int n) {
    int i = blockIdx.x * blockDim.x + threadIdx.x;
    if (i == 0) row_ptr[0] = 0;
    if (i < n) row_ptr[i + 1] += boff[i >> 10];
}

__global__ void scan3p(const int* __restrict__ partial, const int* __restrict__ pincl,
                       const int* __restrict__ boff, int* __restrict__ base,
                       int* __restrict__ part_off, int E) {
    int i = blockIdx.x * blockDim.x + threadIdx.x;
    if (i < TOTP) {
        int v = pincl[i] + boff[i >> 10] - partial[i];
        base[i] = v;
        if ((i & (NCHUNK - 1)) == 0) part_off[i / NCHUNK] = v;
    }
    if (i == 0) part_off[NBUCK] = E;
}

__global__ __launch_bounds__(256) void partition_edges(const int* __restrict__ src,
                                                       const int* __restrict__ dst,
                                                       const int* __restrict__ base,
                                                       unsigned* __restrict__ part,
                                                       int E, int chunk) {
    __shared__ int cur[NBUCK];
    int t = threadIdx.x, c = blockIdx.x;
    for (int b = t; b < NBUCK; b += 256) cur[b] = base[b * NCHUNK + c];
    __syncthreads();
    int lo = c * chunk, hi = min(lo + chunk, E);
    for (int i = lo + t; i < hi; i += 256) {
        int s = src[i], d = dst[i];
        int pos = atomicAdd(&cur[d >> 7], 1);
        part[pos] = (unsigned)s | ((unsigned)(d & (BROWS - 1)) << 17);
    }
}

__global__ __launch_bounds__(256) void deg_dis(const unsigned* __restrict__ part,
                                               const int* __restrict__ part_off,
                                               int* __restrict__ pdeg,
                                               float* __restrict__ dis, int n) {
    __shared__ int cnt[BROWS];
    int t = threadIdx.x, b = blockIdx.x;
    int r0 = b * BROWS;
    if (t < BROWS) cnt[t] = 0;
    __syncthreads();
    for (int i = part_off[b] + t; i < part_off[b + 1]; i += 256)
        atomicAdd(&cnt[part[i] >> 17], 1);
    __syncthreads();
    int nrows = min(BROWS, n - r0);
    if (t < nrows) {
        int dg = cnt[t];
        pdeg[r0 + t] = dg;                          // raw; scan1 applies pad8
        dis[r0 + t] = rsqrtf((float)(dg + 1));
    }
}

// stage/cne hold BYTE offsets (src * 128); pad slots -> N_NODES*128 (zero row).
__global__ __launch_bounds__(256) void build_csr(const unsigned* __restrict__ part,
                                                 const int* __restrict__ part_off,
                                                 const int* __restrict__ row_ptr,
                                                 unsigned* __restrict__ cne, int n) {
    __shared__ int fill[BROWS];
    __shared__ unsigned stage[CAP];
    int b = blockIdx.x;
    int r0 = b * BROWS;
    int t = threadIdx.x;
    int nrows = min(BROWS, n - r0);
    int base = row_ptr[r0];
    int region = row_ptr[r0 + nrows] - base;
    for (int r = t; r < nrows; r += 256) fill[r] = row_ptr[r0 + r] - base;
    int i0 = part_off[b], i1 = part_off[b + 1];
    if (region <= CAP) {
        for (int i = t; i < region; i += 256) stage[i] = (unsigned)N_NODES << 7;
        __syncthreads();
        for (int i = i0 + t; i < i1; i += 256) {
            unsigned pe = part[i];
            int pos = atomicAdd(&fill[pe >> 17], 1);
            stage[pos] = (pe & 0x1FFFFu) << 7;
        }
        __syncthreads();
        for (int i = t; i < region; i += 256) cne[base + i] = stage[i];
    } else {
        for (int i = t; i < region; i += 256) cne[base + i] = (unsigned)N_NODES << 7;
        __syncthreads();
        for (int i = i0 + t; i < i1; i += 256) {
            unsigned pe = part[i];
            int pos = atomicAdd(&fill[pe >> 17], 1);
            cne[base + pos] = (pe & 0x1FFFFu) << 7;
        }
    }
}

// ---------------- per-layer compute ----------------

// MFMA GEMM: out[row][col] = (half) dis[row] * sum_k X[row][k] * W[k][col]
// XT = float (layer 1) or _Float16 (h from previous layer; A-frag = direct 16 B load).
// B-fragments built in-register from fp32 W. Layouts verified (R11/R12 + guide m89/m91).
template <int K, typename XT>
__global__ __launch_bounds__(256) void gemm_mfma(const XT* __restrict__ X,
                                                 const float* __restrict__ W,
                                                 const float* __restrict__ dis,
                                                 __half* __restrict__ out, int n) {
    const int KS = K / 32;
    int wave = threadIdx.x >> 6, lane = threadIdx.x & 63;
    int quad = lane >> 4, l16 = lane & 15;
    h8 b[4][KS];
#pragma unroll
    for (int ct = 0; ct < 4; ct++)
#pragma unroll
        for (int ks = 0; ks < KS; ks++)
#pragma unroll
            for (int j = 0; j < 8; j++)
                b[ct][ks][j] = (_Float16)W[(ks * 32 + quad * 8 + j) * HID + ct * 16 + l16];
    int ntile = n >> 4;
    int wpb = blockDim.x >> 6;
    int stride = gridDim.x * wpb;
    for (int rt = blockIdx.x * wpb + wave; rt < ntile; rt += stride) {
        int row0 = rt << 4;
        const XT* xr = X + (size_t)(row0 + l16) * K + quad * 8;
        f4 acc[4];
#pragma unroll
        for (int ct = 0; ct < 4; ct++) acc[ct] = (f4)(0.f);
#pragma unroll
        for (int ks = 0; ks < KS; ks++) {
            h8 a;
            if constexpr (__is_same(XT, float)) {
                float4 xa = *(const float4*)(xr + ks * 32);
                float4 xb = *(const float4*)(xr + ks * 32 + 4);
                a[0] = (_Float16)xa.x; a[1] = (_Float16)xa.y;
                a[2] = (_Float16)xa.z; a[3] = (_Float16)xa.w;
                a[4] = (_Float16)xb.x; a[5] = (_Float16)xb.y;
                a[6] = (_Float16)xb.z; a[7] = (_Float16)xb.w;
            } else {
                a = *(const h8*)(xr + ks * 32);
            }
#pragma unroll
            for (int ct = 0; ct < 4; ct++)
                acc[ct] = __builtin_amdgcn_mfma_f32_16x16x32_f16(a, b[ct][ks], acc[ct], 0, 0, 0);
        }
        int r0 = row0 + quad * 4;
        float4 dv = *(const float4*)(dis + r0);
        float dd[4] = {dv.x, dv.y, dv.z, dv.w};
#pragma unroll
        for (int reg = 0; reg < 4; reg++) {
            __half* orow = out + (size_t)(r0 + reg) * HID + l16;
            orow[0]  = __float2half(dd[reg] * acc[0][reg]);
            orow[16] = __float2half(dd[reg] * acc[1][reg]);
            orow[32] = __float2half(dd[reg] * acc[2][reg]);
            orow[48] = __float2half(dd[reg] * acc[3][reg]);
        }
    }
}

// out[row] = relu( dis[row] * (tmp2[row] + sum_cols tmp2[col]) + bias ); pads read zero row N.
// half2 pairing: lane l -> column pair (2m,2m+1), m=l&31. Half hh takes edges 4*hh..4*hh+3
// of each 8-edge group: ONE int4 idx load per lane per group (no cndmask). cne holds byte
// offsets -> gather address is a single v_add onto the lane's base. Depth-2 pipeline:
// 16 edges in flight per wave; indices prefetched one group ahead.
template <typename OutT>
__global__ __launch_bounds__(256) void aggregate(const __half* __restrict__ tmp,
                                                 const float* __restrict__ dis,
                                                 const int* __restrict__ row_ptr,
                                                 const unsigned* __restrict__ cne,
                                                 const float* __restrict__ bias,
                                                 OutT* __restrict__ out, int n) {
    int wave = threadIdx.x >> 6, lane = threadIdx.x & 63;
    int m = lane & 31, hh = lane >> 5;
    const char* tbase = (const char*)tmp + 4 * m;   // lane's column-pair byte base
    int wpb = blockDim.x >> 6;
    int stride = gridDim.x * wpb;
    float2 blv = *(const float2*)(bias + 2 * m);
    for (int row = blockIdx.x * wpb + wave; row < n; row += stride) {
        float dr = dis[row];
        float ax0 = 0.f, ay0 = 0.f, ax1 = 0.f, ay1 = 0.f;
        float ax2 = 0.f, ay2 = 0.f, ax3 = 0.f, ay3 = 0.f;
        int s = row_ptr[row], e = row_ptr[row + 1];
        int ng = (e - s) >> 3;   // 8-edge groups (rows padded to 8)
        if (ng > 0) {
            const uint4* ip = (const uint4*)(cne + s) + hh;   // my half's int4 of group 0
            uint4 A = ip[0];
            __half2 g0 = *(const __half2*)(tbase + A.x);
            __half2 g1 = *(const __half2*)(tbase + A.y);
            __half2 g2 = *(const __half2*)(tbase + A.z);
            __half2 g3 = *(const __half2*)(tbase + A.w);
            uint4 B;
            if (ng > 1) B = ip[2];
            for (int g = 1; g < ng; g++) {
                __half2 u0 = *(const __half2*)(tbase + B.x);
                __half2 u1 = *(const __half2*)(tbase + B.y);
                __half2 u2 = *(const __half2*)(tbase + B.z);
                __half2 u3 = *(const __half2*)(tbase + B.w);
                if (g + 1 < ng) B = ip[2 * (g + 1)];
                float2 f0 = __half22float2(g0), f1 = __half22float2(g1);
                float2 f2 = __half22float2(g2), f3 = __half22float2(g3);
                ax0 += f0.x; ay0 += f0.y; ax1 += f1.x; ay1 += f1.y;
                ax2 += f2.x; ay2 += f2.y; ax3 += f3.x; ay3 += f3.y;
                g0 = u0; g1 = u1; g2 = u2; g3 = u3;
            }
            float2 f0 = __half22float2(g0), f1 = __half22float2(g1);
            float2 f2 = __half22float2(g2), f3 = __half22float2(g3);
            ax0 += f0.x; ay0 += f0.y; ax1 += f1.x; ay1 += f1.y;
            ax2 += f2.x; ay2 += f2.y; ax3 += f3.x; ay3 += f3.y;
        }
        float sx = (ax0 + ax1) + (ax2 + ax3);
        float sy = (ay0 + ay1) + (ay2 + ay3);
        sx += __shfl_xor(sx, 32);
        sy += __shfl_xor(sy, 32);
        float2 selff = __half22float2(*(const __half2*)(tbase + (size_t)row * 128));
        float rx = fmaxf(dr * (selff.x + sx) + blv.x, 0.f);
        float ry = fmaxf(dr * (selff.y + sy) + blv.y, 0.f);
        if (hh == 0) {
            if constexpr (__is_same(OutT, __half)) {
                *(__half2*)(out + row * HID + 2 * m) = __floats2half2_rn(rx, ry);
            } else {
                *(float2*)(out + row * HID + 2 * m) = make_float2(rx, ry);
            }
        }
    }
}

__global__ __launch_bounds__(256) void pool_kernel(const float* __restrict__ h,
                                                   const int* __restrict__ batch,
                                                   const float* __restrict__ Wout,
                                                   const float* __restrict__ bout,
                                                   float* __restrict__ d_out, int n) {
    __shared__ float ssum[4][64];
    __shared__ float smax[4][64];
    int g = blockIdx.x;
    int wave = threadIdx.x >> 6, j = threadIdx.x & 63;
    int lo = 0, hi = n;
    while (lo < hi) { int mid = (lo + hi) >> 1; if (batch[mid] < g) lo = mid + 1; else hi = mid; }
    int start = lo;
    hi = n;
    while (lo < hi) { int mid = (lo + hi) >> 1; if (batch[mid] < g + 1) lo = mid + 1; else hi = mid; }
    int end = lo;

    float sum = 0.f, mx = 0.f;
    for (int i = start + wave; i < end; i += 4) {
        float v = h[(size_t)i * HID + j];
        sum += v;
        mx = fmaxf(mx, v);
    }
    ssum[wave][j] = sum;
    smax[wave][j] = mx;
    __syncthreads();
    if (wave == 0) {
        sum = (ssum[0][j] + ssum[1][j]) + (ssum[2][j] + ssum[3][j]);
        mx = fmaxf(fmaxf(smax[0][j], smax[1][j]), fmaxf(smax[2][j], smax[3][j]));
        float cnt = (float)(end - start);
        float mean = sum / fmaxf(cnt, 1.f);
        float* pooled = d_out + NUM_GRAPHS;
        pooled[(size_t)g * (2 * HID) + j] = mean;
        pooled[(size_t)g * (2 * HID) + HID + j] = mx;
        float c = mean * Wout[j] + mx * Wout[HID + j];
#pragma unroll
        for (int off = 32; off; off >>= 1) c += __shfl_down(c, off);
        if (j == 0) d_out[g] = c + bout[0];
    }
}

// ---------------- launch ----------------

extern "C" void kernel_launch(void* const* d_in, const int* in_sizes, int n_in,
                              void* d_out, int out_size, void* d_ws, size_t ws_size,
                              hipStream_t stream) {
    const float* x    = (const float*)d_in[0];
    const int*   edge = (const int*)d_in[1];
    const int*   batch= (const int*)d_in[2];
    const float* W1 = (const float*)d_in[3];  const float* b1 = (const float*)d_in[4];
    const float* W2 = (const float*)d_in[5];  const float* b2 = (const float*)d_in[6];
    const float* W3 = (const float*)d_in[7];  const float* b3 = (const float*)d_in[8];
    const float* W4 = (const float*)d_in[9];  const float* b4 = (const float*)d_in[10];
    const float* Wout = (const float*)d_in[11]; const float* bout = (const float*)d_in[12];
    float* out = (float*)d_out;

    const int N = N_NODES;
    const int E = in_sizes[1] / 2;
    const int* src = edge;
    const int* dst = edge + E;
    const int chunk = (E + NCHUNK - 1) / NCHUNK;

    char* p = (char*)d_ws;
    auto alloc = [&](size_t bytes) -> char* {
        char* r = p;
        p += (bytes + 255) & ~(size_t)255;
        return r;
    };
    int*      pdeg     = (int*)alloc((size_t)N * 4);
    int*      row_ptr  = (int*)alloc((size_t)(N + 1) * 4);
    int*      partial  = (int*)alloc((size_t)TOTP * 4);
    int*      pincl    = (int*)alloc((size_t)TOTP * 4);
    int*      pbase    = (int*)alloc((size_t)TOTP * 4);
    int*      part_off = (int*)alloc((size_t)(NBUCK + 1) * 4);
    unsigned* part     = (unsigned*)alloc((size_t)1600000 * 4);
    unsigned* cne      = (unsigned*)alloc((size_t)CNE_MAX * 4);
    float*    dis      = (float*)alloc((size_t)N * 4);
    int*      bsum     = (int*)alloc(256 * 4);
    int*      boff     = (int*)alloc(256 * 4);
    __half*   tmp      = (__half*)alloc((size_t)(N + 1) * HID * 2);
    float*    hA       = (float*)alloc((size_t)N * HID * 4);
    __half*   hH       = (__half*)hA;   // fp16 h aliases front of hA (hA dead until agg4)

    hipMemsetAsync(tmp + (size_t)N * HID, 0, HID * 2, stream);   // zero pad row N

    hist_partial<<<NCHUNK, 256, 0, stream>>>(dst, partial, E, chunk);
    int nbp = (TOTP + 1023) / 1024;   // 196
    scan1<<<nbp, 256, 0, stream>>>(partial, pincl, bsum, TOTP, 0);
    scan2<<<1, 256, 0, stream>>>(bsum, boff, nbp);
    scan3p<<<(TOTP + 255) / 256, 256, 0, stream>>>(partial, pincl, boff, pbase, part_off, E);
    partition_edges<<<NCHUNK, 256, 0, stream>>>(src, dst, pbase, part, E, chunk);
    deg_dis<<<NBUCK, 256, 0, stream>>>(part, part_off, pdeg, dis, N);

    int nb = (N + 1023) / 1024;   // 98
    scan1<<<nb, 256, 0, stream>>>(pdeg, row_ptr + 1, bsum, N, 1);
    scan2<<<1, 256, 0, stream>>>(bsum, boff, nb);
    scan3<<<(N + 255) / 256, 256, 0, stream>>>(row_ptr, boff, N);
    build_csr<<<NBUCK, 256, 0, stream>>>(part, part_off, row_ptr, cne, N);

    const int AGG_BLOCKS = 2048;
    const int GEMM_BLOCKS = 1024;

    gemm_mfma<IN_DIM, float><<<GEMM_BLOCKS, 256, 0, stream>>>(x, W1, dis, tmp, N);
    aggregate<__half><<<AGG_BLOCKS, 256, 0, stream>>>(tmp, dis, row_ptr, cne, b1, hH, N);
    gemm_mfma<HID, _Float16><<<GEMM_BLOCKS, 256, 0, stream>>>((_Float16*)hH, W2, dis, tmp, N);
    aggregate<__half><<<AGG_BLOCKS, 256, 0, stream>>>(tmp, dis, row_ptr, cne, b2, hH, N);
    gemm_mfma<HID, _Float16><<<GEMM_BLOCKS, 256, 0, stream>>>((_Float16*)hH, W3, dis, tmp, N);
    aggregate<__half><<<AGG_BLOCKS, 256, 0, stream>>>(tmp, dis, row_ptr, cne, b3, hH, N);
    gemm_mfma<HID, _Float16><<<GEMM_BLOCKS, 256, 0, stream>>>((_Float16*)hH, W4, dis, tmp, N);
    aggregate<float><<<AGG_BLOCKS, 256, 0, stream>>>(tmp, dis, row_ptr, cne, b4, hA, N);

    pool_kernel<<<NUM_GRAPHS, 256, 0, stream>>>(hA, batch, Wout, bout, out, N);
}